// Round 6
// baseline (2688.787 us; speedup 1.0000x reference)
//
#include <hip/hip_runtime.h>
#include <stdint.h>
#include <math.h>
#include <algorithm>

#define NS 8
#define NA 1024
#define NK 5
#define MAXIT 30
#define TOLER 1e-5
#define NBLK_LOOP 256

// ---------------- host-side threefry-2x32 (JAX-compatible) ----------------
static inline void tf2x32(uint32_t k0, uint32_t k1, uint32_t c0, uint32_t c1,
                          uint32_t& o0, uint32_t& o1) {
  uint32_t ks2 = k0 ^ k1 ^ 0x1BD11BDAu;
  uint32_t x0 = c0 + k0, x1 = c1 + k1;
  auto rot = [](uint32_t x, int r) { return (x << r) | (x >> (32 - r)); };
  auto R4 = [&](int r0, int r1, int r2, int r3) {
    x0 += x1; x1 = rot(x1, r0); x1 ^= x0;
    x0 += x1; x1 = rot(x1, r1); x1 ^= x0;
    x0 += x1; x1 = rot(x1, r2); x1 ^= x0;
    x0 += x1; x1 = rot(x1, r3); x1 ^= x0;
  };
  R4(13, 15, 26, 6);  x0 += k1;  x1 += ks2 + 1u;
  R4(17, 29, 16, 24); x0 += ks2; x1 += k0 + 2u;
  R4(13, 15, 26, 6);  x0 += k0;  x1 += k1 + 3u;
  R4(17, 29, 16, 24); x0 += k1;  x1 += ks2 + 4u;
  R4(13, 15, 26, 6);  x0 += ks2; x1 += k0 + 5u;
  o0 = x0; o1 = x1;
}

struct InitIdx { int v[NS * NK]; };

// jax_threefry_partitionable=True semantics (verified R3/R5: PASS)
static void compute_init_indices(InitIdx& out) {
  const uint32_t rk0 = 0, rk1 = 42;
  for (int s = 0; s < NS; s++) {
    uint32_t k0, k1;
    tf2x32(rk0, rk1, 0u, (uint32_t)s, k0, k1);
    uint32_t sk0, sk1;
    tf2x32(k0, k1, 0u, 1u, sk0, sk1);
    uint32_t bits[NA];
    for (int i = 0; i < NA; i++) {
      uint32_t b0, b1;
      tf2x32(sk0, sk1, 0u, (uint32_t)i, b0, b1);
      bits[i] = b0 ^ b1;
    }
    int idx[NA];
    for (int i = 0; i < NA; i++) idx[i] = i;
    std::stable_sort(idx, idx + NA, [&](int x, int y) { return bits[x] < bits[y]; });
    for (int c = 0; c < NK; c++) out.v[s * NK + c] = idx[c];
  }
}

// ---------------- device helpers ----------------
__device__ __forceinline__ double wave_reduce64(double v) {
#pragma unroll
  for (int m = 32; m > 0; m >>= 1) v += __shfl_xor(v, m, 64);
  return v;
}

__device__ __forceinline__ double blk_sum_1024(double v, double* red16) {
  double w = wave_reduce64(v);
  if ((threadIdx.x & 63) == 0) red16[threadIdx.x >> 6] = w;
  __syncthreads();
  double tot = 0.0;
#pragma unroll
  for (int i = 0; i < 16; i++) tot += red16[i];
  __syncthreads();
  return tot;
}

__device__ __forceinline__ double blk_sum_256(double v, double* red4) {
  double w = wave_reduce64(v);
  if ((threadIdx.x & 63) == 0) red4[threadIdx.x >> 6] = w;
  __syncthreads();
  double tot = red4[0] + red4[1] + red4[2] + red4[3];
  __syncthreads();
  return tot;
}

// Device-scope grid barrier (256 co-resident blocks: capacity 2/CU x 256 CU).
__device__ __forceinline__ void grid_barrier(int* cnt, int* gen) {
  __syncthreads();
  if (threadIdx.x == 0) {
    __threadfence();  // release: drain this block's global writes
    int g = __hip_atomic_load(gen, __ATOMIC_RELAXED, __HIP_MEMORY_SCOPE_AGENT);
    int a = __hip_atomic_fetch_add(cnt, 1, __ATOMIC_ACQ_REL, __HIP_MEMORY_SCOPE_AGENT);
    if (a == NBLK_LOOP - 1) {
      __hip_atomic_store(cnt, 0, __ATOMIC_RELAXED, __HIP_MEMORY_SCOPE_AGENT);
      __hip_atomic_store(gen, g + 1, __ATOMIC_RELEASE, __HIP_MEMORY_SCOPE_AGENT);
    } else {
      while (__hip_atomic_load(gen, __ATOMIC_ACQUIRE, __HIP_MEMORY_SCOPE_AGENT) == g)
        __builtin_amdgcn_s_sleep(2);
    }
    __threadfence();  // acquire: invalidate L1 before re-reading peers' data
  }
  __syncthreads();
}

// ---------------- pre-kernels ----------------
__global__ __launch_bounds__(256) void k_rstd(const float* __restrict__ cov, double* __restrict__ rstd) {
  int gid = blockIdx.x * 256 + threadIdx.x;
  if (gid >= NS * NA) return;
  int s = gid >> 10, a = gid & 1023;
  double d = (double)cov[(size_t)s * NA * NA + (size_t)a * NA + a];
  rstd[gid] = 1.0 / sqrt(d);
}

__global__ __launch_bounds__(256) void k_xn(const float* __restrict__ cov, const double* __restrict__ rstd,
                                            double* __restrict__ xn) {
  int w = blockIdx.x;  // 512
  int s = w >> 6;
  __shared__ double rsh[NA];
  for (int j = threadIdx.x; j < NA; j += 256) rsh[j] = rstd[s * NA + j];
  __syncthreads();
  int lane = threadIdx.x & 63, wave = threadIdx.x >> 6;
  const float* covS = cov + (size_t)s * NA * NA;
  for (int q = 0; q < 4; q++) {
    int i = (w & 63) * 16 + wave * 4 + q;
    const float* row = covS + (size_t)i * NA;
    double acc = 0.0;
    for (int j = lane; j < NA; j += 64) {
      double v = (double)row[j] * rsh[j];
      acc += v * v;
    }
    acc = wave_reduce64(acc);
    if (lane == 0) {
      double ri = rsh[i];
      xn[s * NA + i] = acc * ri * ri;
    }
  }
}

__global__ __launch_bounds__(256) void k_centers_init(const float* __restrict__ cov, const double* __restrict__ rstd,
                                                      double* __restrict__ C, InitIdx ii) {
  int w = blockIdx.x;  // 40
  int s = w / NK, k = w % NK;
  int idx = ii.v[s * NK + k];
  const float* row = cov + (size_t)s * NA * NA + (size_t)idx * NA;
  const double* rs = rstd + s * NA;
  double ri = rs[idx];
  for (int j = threadIdx.x; j < NA; j += 256)
    C[((size_t)s * NK + k) * NA + j] = (double)row[j] * ri * rs[j];
}

__global__ void k_state_init(double* pot, int* conv, int* bar) {
  int t = threadIdx.x;
  if (t < NS) { pot[t] = INFINITY; conv[t] = 0; }
  if (t < 64) bar[t] = 0;  // bar[0]=cnt, bar[32]=gen (separate cachelines)
}

// ---------------- persistent KMeans loop ----------------
// 256 blocks x 1024 thr: s = blk>>5, 32 rows/block, early exit when all conv.
__global__ __launch_bounds__(1024) void k_loop(const float* __restrict__ cov, const double* __restrict__ rstd,
                                               const double* __restrict__ xn, double* __restrict__ C,
                                               int* __restrict__ ixs, double* __restrict__ mind,
                                               double* __restrict__ pot, int* __restrict__ conv,
                                               int* __restrict__ bar) {
  int blk = blockIdx.x, s = blk >> 5, rblk = blk & 31;
  int t = threadIdx.x, lane = t & 63, wid = t >> 6;
  __shared__ double sh5[NK][NA];  // Cs (phase A) / masks (phase B), 40 KB
  __shared__ double red16[16];
  __shared__ int flags[2];
  const float* covS = cov + (size_t)s * NA * NA;
  int* bcnt = bar, * bgen = bar + 32;
  for (int it = 0; it < MAXIT; it++) {
    if (t == 0) {
      int sum = 0;
#pragma unroll
      for (int q = 0; q < NS; q++)
        sum += __hip_atomic_load(conv + q, __ATOMIC_RELAXED, __HIP_MEMORY_SCOPE_AGENT);
      flags[0] = __hip_atomic_load(conv + s, __ATOMIC_RELAXED, __HIP_MEMORY_SCOPE_AGENT);
      flags[1] = (sum == NS);
    }
    __syncthreads();
    int frozen = flags[0];
    if (flags[1]) break;  // all samples converged: uniform across grid
    if (!frozen) {
      // ---- phase A: assignment ----
      double rj = rstd[s * NA + t];
      double sq[NK];
#pragma unroll
      for (int k = 0; k < NK; k++) {
        double c = C[((size_t)s * NK + k) * NA + t];
        sh5[k][t] = c * rj;
        sq[k] = c * c;
      }
      double cn[NK];
#pragma unroll
      for (int k = 0; k < NK; k++) cn[k] = blk_sum_1024(sq[k], red16);
#pragma unroll
      for (int r2 = 0; r2 < 2; r2++) {
        int i = rblk * 32 + wid * 2 + r2;
        const float* row = covS + (size_t)i * NA;
        double xi = xn[s * NA + i];
        double ri = rstd[s * NA + i];
        double a0 = 0, a1 = 0, a2 = 0, a3 = 0, a4 = 0;
#pragma unroll
        for (int c = 0; c < 16; c++) {
          int j = lane + (c << 6);
          double cv = (double)row[j];
          a0 += cv * sh5[0][j]; a1 += cv * sh5[1][j]; a2 += cv * sh5[2][j];
          a3 += cv * sh5[3][j]; a4 += cv * sh5[4][j];
        }
        a0 = wave_reduce64(a0); a1 = wave_reduce64(a1); a2 = wave_reduce64(a2);
        a3 = wave_reduce64(a3); a4 = wave_reduce64(a4);
        if (lane == 0) {
          double dots[5] = {a0, a1, a2, a3, a4};
          double best = INFINITY;
          int bk = 0;
#pragma unroll
          for (int k = 0; k < NK; k++) {
            double d = xi + cn[k] - 2.0 * ri * dots[k];
            if (d < 0.0) d = 0.0;
            if (d < best) { best = d; bk = k; }  // first-min like jnp.argmin
          }
          ixs[s * NA + i] = bk;
          mind[s * NA + i] = best;
        }
      }
    }
    grid_barrier(bcnt, bgen);
    if (!frozen) {
      // ---- phase B: center update via symmetry (row-major coalesced) + pot ----
      int myc = ixs[s * NA + t];
      double rt = rstd[s * NA + t];
#pragma unroll
      for (int k = 0; k < NK; k++) sh5[k][t] = (myc == k) ? rt : 0.0;
      double cntk[NK];
#pragma unroll
      for (int k = 0; k < NK; k++) cntk[k] = blk_sum_1024((myc == k) ? 1.0 : 0.0, red16);
#pragma unroll
      for (int r2 = 0; r2 < 2; r2++) {
        int j = rblk * 32 + wid * 2 + r2;
        const float* row = covS + (size_t)j * NA;
        double a0 = 0, a1 = 0, a2 = 0, a3 = 0, a4 = 0;
#pragma unroll
        for (int c = 0; c < 16; c++) {
          int jj = lane + (c << 6);
          double cv = (double)row[jj];
          a0 += cv * sh5[0][jj]; a1 += cv * sh5[1][jj]; a2 += cv * sh5[2][jj];
          a3 += cv * sh5[3][jj]; a4 += cv * sh5[4][jj];
        }
        a0 = wave_reduce64(a0); a1 = wave_reduce64(a1); a2 = wave_reduce64(a2);
        a3 = wave_reduce64(a3); a4 = wave_reduce64(a4);
        if (lane == 0) {
          double rjj = rstd[s * NA + j];
          double* CS = C + (size_t)s * NK * NA;
          double aa[5] = {a0, a1, a2, a3, a4};
#pragma unroll
          for (int k = 0; k < NK; k++)
            if (cntk[k] > 0.0) CS[(size_t)k * NA + j] = aa[k] * rjj / cntk[k];
          // empty cluster: keep previous center
        }
      }
      if (rblk == 0) {
        double p = blk_sum_1024(mind[s * NA + t], red16);
        if (t == 0) {
          double prev = pot[s];
          pot[s] = p;
          if (!(fabs(p - prev) >= TOLER)) conv[s] = 1;  // freeze (while-cond fails)
        }
      }
    }
    grid_barrier(bcnt, bgen);
  }
}

// ---------------- post-processing ----------------
__global__ __launch_bounds__(256) void k_members(const int* __restrict__ ixs, int* __restrict__ g,
                                                 int* __restrict__ cnt, int* __restrict__ off5,
                                                 int* __restrict__ boff) {
  int s = blockIdx.x, t = threadIdx.x;
  __shared__ int sc[NK][256];
  __shared__ int base[NK];
  const int* ix = ixs + s * NA;
  int my[4];
  int lc[NK] = {0, 0, 0, 0, 0};
#pragma unroll
  for (int q = 0; q < 4; q++) { my[q] = ix[t * 4 + q]; lc[my[q]]++; }
#pragma unroll
  for (int k = 0; k < NK; k++) sc[k][t] = lc[k];
  __syncthreads();
  for (int off = 1; off < 256; off <<= 1) {
    int v[NK];
#pragma unroll
    for (int k = 0; k < NK; k++) v[k] = (t >= off) ? sc[k][t - off] : 0;
    __syncthreads();
#pragma unroll
    for (int k = 0; k < NK; k++) sc[k][t] += v[k];
    __syncthreads();
  }
  if (t == 0) {
    int b = 0, bo = 0;
    for (int k = 0; k < NK; k++) {
      int tot = sc[k][255];
      base[k] = b;
      cnt[s * NK + k] = tot;
      off5[s * NK + k] = b;
      boff[s * NK + k] = bo;
      b += tot;
      bo += tot * tot;
    }
  }
  __syncthreads();
  int pos[NK];
#pragma unroll
  for (int k = 0; k < NK; k++) pos[k] = base[k] + sc[k][t] - lc[k];
#pragma unroll
  for (int q = 0; q < 4; q++) {
    int k = my[q];
    int p = pos[k]++;
    g[s * NA + p] = t * 4 + q;  // stable ascending asset order within cluster
  }
}

// One-time compact gather: cluster k of sample s -> dense n x n f32 at lda=n.
__global__ __launch_bounds__(1024) void k_gatherB(const float* __restrict__ cov, const int* __restrict__ g,
                                                  const int* __restrict__ cnt, const int* __restrict__ off5,
                                                  const int* __restrict__ boff, float* __restrict__ B) {
  int w = blockIdx.x;  // 40
  int s = w / NK, k = w % NK;
  int n = cnt[s * NK + k];
  if (n == 0) return;
  int off = off5[s * NK + k];
  __shared__ int gs[NA];
  int t = threadIdx.x, lane = t & 63, wid = t >> 6;
  if (t < n) gs[t] = g[s * NA + off + t];
  __syncthreads();
  const float* covS = cov + (size_t)s * NA * NA;
  float* Bk = B + (size_t)s * NA * NA + (size_t)boff[s * NK + k];
  for (int i = wid; i < n; i += 16) {
    const float* row = covS + (size_t)gs[i] * NA;
    float* out = Bk + (size_t)i * n;
    for (int j = lane; j < n; j += 64) out[j] = row[gs[j]];
  }
}

// f64 CG on the compact block: Sigma_cc x = 1; normalize; scatter.
__global__ __launch_bounds__(1024) void k_cg_comp(const float* __restrict__ B, const int* __restrict__ g,
                                                  const int* __restrict__ cnt, const int* __restrict__ off5,
                                                  const int* __restrict__ boff, double* __restrict__ walloc) {
  int w = blockIdx.x;  // 40
  int s = w / NK, k = w % NK;
  int n = cnt[s * NK + k];
  if (n == 0) return;
  int off = off5[s * NK + k];
  const float* A = B + (size_t)s * NA * NA + (size_t)boff[s * NK + k];
  __shared__ double xv[NA], rv[NA], pv[NA], ap[NA];
  __shared__ int gs[NA];
  __shared__ double red16[16];
  int t = threadIdx.x, lane = t & 63, wid = t >> 6;
  if (t < n) {
    gs[t] = g[s * NA + off + t];
    xv[t] = 0.0; rv[t] = 1.0; pv[t] = 1.0;
  }
  double rr = (double)n;
  __syncthreads();
  for (int iter = 0; iter < 150; iter++) {
    for (int i = wid; i < n; i += 16) {
      const float* row = A + (size_t)i * n;
      double acc = 0.0;
      for (int j = lane; j < n; j += 64) acc += (double)row[j] * pv[j];
      acc = wave_reduce64(acc);
      if (lane == 0) ap[i] = acc;
    }
    __syncthreads();
    double pp = (t < n) ? pv[t] * ap[t] : 0.0;
    double pap = blk_sum_1024(pp, red16);
    double alpha = rr / pap;
    double rp = 0.0;
    if (t < n) {
      xv[t] += alpha * pv[t];
      double rn = rv[t] - alpha * ap[t];
      rv[t] = rn;
      rp = rn * rn;
    }
    double rrn = blk_sum_1024(rp, red16);
    if (rrn < 1e-20 * (double)n) break;  // rel resid 1e-10; uniform branch
    double beta = rrn / rr;
    rr = rrn;
    if (t < n) pv[t] = rv[t] + beta * pv[t];
    __syncthreads();
  }
  double dp = (t < n) ? xv[t] : 0.0;
  double denom = blk_sum_1024(dp, red16);
  if (t < n) walloc[s * NA + gs[t]] = xv[t] / denom;
}

// Fallback (ws too small for compact B): R5's full-row CG — verified PASS.
__global__ __launch_bounds__(1024) void k_cg_full(const float* __restrict__ cov,
                                                  const int* __restrict__ g, const int* __restrict__ cnt,
                                                  const int* __restrict__ off5, double* __restrict__ walloc) {
  int w = blockIdx.x;
  int s = w / NK, k = w % NK;
  int n = cnt[s * NK + k];
  if (n == 0) return;
  int off = off5[s * NK + k];
  const float* covS = cov + (size_t)s * NA * NA;
  __shared__ double pfull[NA];
  __shared__ double xv[NA], rv[NA], pv[NA], ap[NA];
  __shared__ int gs[NA];
  __shared__ double red16[16];
  int t = threadIdx.x, lane = t & 63, wid = t >> 6;
  if (t < n) {
    gs[t] = g[s * NA + off + t];
    xv[t] = 0.0; rv[t] = 1.0; pv[t] = 1.0;
  }
  double rr = (double)n;
  __syncthreads();
  for (int iter = 0; iter < 150; iter++) {
    pfull[t] = 0.0;
    __syncthreads();
    if (t < n) pfull[gs[t]] = pv[t];
    __syncthreads();
    for (int i = wid; i < n; i += 16) {
      const float* row = covS + (size_t)gs[i] * NA;
      double acc = 0.0;
#pragma unroll
      for (int c = 0; c < 16; c++) {
        int j = lane + (c << 6);
        acc += (double)row[j] * pfull[j];
      }
      acc = wave_reduce64(acc);
      if (lane == 0) ap[i] = acc;
    }
    __syncthreads();
    double pp = (t < n) ? pv[t] * ap[t] : 0.0;
    double pap = blk_sum_1024(pp, red16);
    double alpha = rr / pap;
    double rp = 0.0;
    if (t < n) {
      xv[t] += alpha * pv[t];
      double rn = rv[t] - alpha * ap[t];
      rv[t] = rn;
      rp = rn * rn;
    }
    double rrn = blk_sum_1024(rp, red16);
    if (rrn < 1e-20 * (double)n) break;
    double beta = rrn / rr;
    rr = rrn;
    if (t < n) pv[t] = rv[t] + beta * pv[t];
    __syncthreads();
  }
  double dp = (t < n) ? xv[t] : 0.0;
  double denom = blk_sum_1024(dp, red16);
  if (t < n) walloc[s * NA + gs[t]] = xv[t] / denom;
}

__global__ __launch_bounds__(256) void k_intery(const float* __restrict__ cov, const double* __restrict__ walloc,
                                                const int* __restrict__ g, const int* __restrict__ cnt,
                                                const int* __restrict__ off5, double* __restrict__ y2) {
  int w = blockIdx.x;  // 160
  int s = w / 20, rem = w % 20, k = rem / 4, seg = rem % 4;
  int n = cnt[s * NK + k], off = off5[s * NK + k];
  int t = threadIdx.x;
  __shared__ int gsl[NA];
  __shared__ double wl[NA];
  for (int i = t; i < n; i += 256) {
    int a = g[s * NA + off + i];
    gsl[i] = a;
    wl[i] = walloc[s * NA + a];
  }
  __syncthreads();
  int j = seg * 256 + t;
  const float* covS = cov + (size_t)s * NA * NA;
  double acc = 0.0;
  for (int i = 0; i < n; i++) acc += wl[i] * (double)covS[(size_t)gsl[i] * NA + j];
  y2[((size_t)s * NK + k) * NA + j] = acc;
}

__global__ __launch_bounds__(256) void k_icov(const double* __restrict__ y2, const double* __restrict__ walloc,
                                              const int* __restrict__ ixs, double* __restrict__ w_inter) {
  int s = blockIdx.x, t = threadIdx.x;
  __shared__ double red4[4];
  __shared__ double ic[NK * NK];
  for (int k = 0; k < NK; k++) {
    double p0 = 0, p1 = 0, p2 = 0, p3 = 0, p4 = 0;
    for (int j = t; j < NA; j += 256) {
      double v = y2[((size_t)s * NK + k) * NA + j] * walloc[s * NA + j];
      int c = ixs[s * NA + j];
      p0 += (c == 0) ? v : 0.0;
      p1 += (c == 1) ? v : 0.0;
      p2 += (c == 2) ? v : 0.0;
      p3 += (c == 3) ? v : 0.0;
      p4 += (c == 4) ? v : 0.0;
    }
    double q0 = blk_sum_256(p0, red4);
    double q1 = blk_sum_256(p1, red4);
    double q2 = blk_sum_256(p2, red4);
    double q3 = blk_sum_256(p3, red4);
    double q4 = blk_sum_256(p4, red4);
    if (t == 0) {
      ic[k * NK + 0] = q0; ic[k * NK + 1] = q1; ic[k * NK + 2] = q2;
      ic[k * NK + 3] = q3; ic[k * NK + 4] = q4;
    }
  }
  __syncthreads();
  if (t == 0) {
    double M[NK * NK], b[NK], z[NK];
    for (int i = 0; i < NK * NK; i++) M[i] = ic[i];
    for (int i = 0; i < NK; i++) b[i] = 1.0;
    for (int c = 0; c < NK; c++) {
      int pr = c;
      double mb = fabs(M[c * NK + c]);
      for (int r = c + 1; r < NK; r++) {
        double a = fabs(M[r * NK + c]);
        if (a > mb) { mb = a; pr = r; }
      }
      if (pr != c) {
        for (int cc = 0; cc < NK; cc++) {
          double tmp = M[c * NK + cc]; M[c * NK + cc] = M[pr * NK + cc]; M[pr * NK + cc] = tmp;
        }
        double tb = b[c]; b[c] = b[pr]; b[pr] = tb;
      }
      double piv = M[c * NK + c];
      for (int r = c + 1; r < NK; r++) {
        double f = M[r * NK + c] / piv;
        for (int cc = c; cc < NK; cc++) M[r * NK + cc] -= f * M[c * NK + cc];
        b[r] -= f * b[c];
      }
    }
    for (int r = NK - 1; r >= 0; r--) {
      double acc = b[r];
      for (int cc = r + 1; cc < NK; cc++) acc -= M[r * NK + cc] * z[cc];
      z[r] = acc / M[r * NK + r];
    }
    double ssum = z[0] + z[1] + z[2] + z[3] + z[4];
    for (int k = 0; k < NK; k++) w_inter[s * NK + k] = z[k] / ssum;
  }
}

__global__ __launch_bounds__(256) void k_final(const double* __restrict__ walloc, const double* __restrict__ w_inter,
                                               const int* __restrict__ ixs, float* __restrict__ out) {
  int gid = blockIdx.x * 256 + threadIdx.x;
  if (gid >= NS * NA) return;
  int s = gid >> 10;
  out[gid] = (float)(walloc[gid] * w_inter[s * NK + ixs[gid]]);
}

// ---------------- launch ----------------
extern "C" void kernel_launch(void* const* d_in, const int* in_sizes, int n_in,
                              void* d_out, int out_size, void* d_ws, size_t ws_size,
                              hipStream_t stream) {
  const float* cov = (const float*)d_in[0];
  float* out = (float*)d_out;
  char* ws = (char*)d_ws;
  size_t o = 0;
  auto alloc = [&](size_t bytes) {
    size_t cur = o;
    o += (bytes + 255) & ~(size_t)255;
    return cur;
  };
  double* C = (double*)(ws + alloc((size_t)NS * NK * NA * 8));
  double* y2 = (double*)(ws + alloc((size_t)NS * NK * NA * 8));
  double* rstd = (double*)(ws + alloc((size_t)NS * NA * 8));
  double* xn = (double*)(ws + alloc((size_t)NS * NA * 8));
  double* mind = (double*)(ws + alloc((size_t)NS * NA * 8));
  double* walloc = (double*)(ws + alloc((size_t)NS * NA * 8));
  int* ixs = (int*)(ws + alloc((size_t)NS * NA * 4));
  int* g = (int*)(ws + alloc((size_t)NS * NA * 4));
  int* cnt = (int*)(ws + alloc((size_t)NS * NK * 4));
  int* off5 = (int*)(ws + alloc((size_t)NS * NK * 4));
  int* boff = (int*)(ws + alloc((size_t)NS * NK * 4));
  int* conv = (int*)(ws + alloc((size_t)NS * 4));
  int* bar = (int*)(ws + alloc(64 * 4));
  double* pot = (double*)(ws + alloc((size_t)NS * 8));
  double* w_inter = (double*)(ws + alloc((size_t)NS * NK * 8));
  size_t bcomp_off = alloc((size_t)NS * NA * NA * 4);  // 33.55 MB, guarded
  float* Bcomp = (float*)(ws + bcomp_off);
  bool use_compact = (ws_size >= o);  // launch-time constant: same graph every call
  (void)in_sizes; (void)n_in; (void)out_size;

  InitIdx ii;
  compute_init_indices(ii);  // data-independent, identical every call

  k_rstd<<<32, 256, 0, stream>>>(cov, rstd);
  k_xn<<<512, 256, 0, stream>>>(cov, rstd, xn);
  k_centers_init<<<40, 256, 0, stream>>>(cov, rstd, C, ii);
  k_state_init<<<1, 64, 0, stream>>>(pot, conv, bar);
  k_loop<<<NBLK_LOOP, 1024, 0, stream>>>(cov, rstd, xn, C, ixs, mind, pot, conv, bar);
  k_members<<<8, 256, 0, stream>>>(ixs, g, cnt, off5, boff);
  if (use_compact) {
    k_gatherB<<<40, 1024, 0, stream>>>(cov, g, cnt, off5, boff, Bcomp);
    k_cg_comp<<<40, 1024, 0, stream>>>(Bcomp, g, cnt, off5, boff, walloc);
  } else {
    k_cg_full<<<40, 1024, 0, stream>>>(cov, g, cnt, off5, walloc);
  }
  k_intery<<<160, 256, 0, stream>>>(cov, walloc, g, cnt, off5, y2);
  k_icov<<<8, 256, 0, stream>>>(y2, walloc, ixs, w_inter);
  k_final<<<32, 256, 0, stream>>>(walloc, w_inter, ixs, out);
}

// Round 7
// 1272.023 us; speedup vs baseline: 2.1138x; 2.1138x over previous
//
#include <hip/hip_runtime.h>
#include <stdint.h>
#include <math.h>
#include <algorithm>

#define NS 8
#define NA 1024
#define NK 5
#define MAXIT 30
#define TOLER 1e-5

// ---------------- host-side threefry-2x32 (JAX-compatible) ----------------
static inline void tf2x32(uint32_t k0, uint32_t k1, uint32_t c0, uint32_t c1,
                          uint32_t& o0, uint32_t& o1) {
  uint32_t ks2 = k0 ^ k1 ^ 0x1BD11BDAu;
  uint32_t x0 = c0 + k0, x1 = c1 + k1;
  auto rot = [](uint32_t x, int r) { return (x << r) | (x >> (32 - r)); };
  auto R4 = [&](int r0, int r1, int r2, int r3) {
    x0 += x1; x1 = rot(x1, r0); x1 ^= x0;
    x0 += x1; x1 = rot(x1, r1); x1 ^= x0;
    x0 += x1; x1 = rot(x1, r2); x1 ^= x0;
    x0 += x1; x1 = rot(x1, r3); x1 ^= x0;
  };
  R4(13, 15, 26, 6);  x0 += k1;  x1 += ks2 + 1u;
  R4(17, 29, 16, 24); x0 += ks2; x1 += k0 + 2u;
  R4(13, 15, 26, 6);  x0 += k0;  x1 += k1 + 3u;
  R4(17, 29, 16, 24); x0 += k1;  x1 += ks2 + 4u;
  R4(13, 15, 26, 6);  x0 += ks2; x1 += k0 + 5u;
  o0 = x0; o1 = x1;
}

struct InitIdx { int v[NS * NK]; };

// jax_threefry_partitionable=True semantics (verified R3/R5/R6: PASS)
static void compute_init_indices(InitIdx& out) {
  const uint32_t rk0 = 0, rk1 = 42;
  for (int s = 0; s < NS; s++) {
    uint32_t k0, k1;
    tf2x32(rk0, rk1, 0u, (uint32_t)s, k0, k1);
    uint32_t sk0, sk1;
    tf2x32(k0, k1, 0u, 1u, sk0, sk1);
    uint32_t bits[NA];
    for (int i = 0; i < NA; i++) {
      uint32_t b0, b1;
      tf2x32(sk0, sk1, 0u, (uint32_t)i, b0, b1);
      bits[i] = b0 ^ b1;
    }
    int idx[NA];
    for (int i = 0; i < NA; i++) idx[i] = i;
    std::stable_sort(idx, idx + NA, [&](int x, int y) { return bits[x] < bits[y]; });
    for (int c = 0; c < NK; c++) out.v[s * NK + c] = idx[c];
  }
}

// ---------------- device helpers ----------------
__device__ __forceinline__ double wave_reduce64(double v) {
#pragma unroll
  for (int m = 32; m > 0; m >>= 1) v += __shfl_xor(v, m, 64);
  return v;
}

__device__ __forceinline__ double blk_sum_1024(double v, double* red16) {
  double w = wave_reduce64(v);
  if ((threadIdx.x & 63) == 0) red16[threadIdx.x >> 6] = w;
  __syncthreads();
  double tot = 0.0;
#pragma unroll
  for (int i = 0; i < 16; i++) tot += red16[i];
  __syncthreads();
  return tot;
}

__device__ __forceinline__ double blk_sum_256(double v, double* red4) {
  double w = wave_reduce64(v);
  if ((threadIdx.x & 63) == 0) red4[threadIdx.x >> 6] = w;
  __syncthreads();
  double tot = red4[0] + red4[1] + red4[2] + red4[3];
  __syncthreads();
  return tot;
}

// ---------------- pre-kernels ----------------
__global__ __launch_bounds__(256) void k_rstd(const float* __restrict__ cov, double* __restrict__ rstd) {
  int gid = blockIdx.x * 256 + threadIdx.x;
  if (gid >= NS * NA) return;
  int s = gid >> 10, a = gid & 1023;
  double d = (double)cov[(size_t)s * NA * NA + (size_t)a * NA + a];
  rstd[gid] = 1.0 / sqrt(d);
}

__global__ __launch_bounds__(256) void k_xn(const float* __restrict__ cov, const double* __restrict__ rstd,
                                            double* __restrict__ xn) {
  int w = blockIdx.x;  // 512
  int s = w >> 6;
  __shared__ double rsh[NA];
  for (int j = threadIdx.x; j < NA; j += 256) rsh[j] = rstd[s * NA + j];
  __syncthreads();
  int lane = threadIdx.x & 63, wave = threadIdx.x >> 6;
  const float* covS = cov + (size_t)s * NA * NA;
  for (int q = 0; q < 4; q++) {
    int i = (w & 63) * 16 + wave * 4 + q;
    const float* row = covS + (size_t)i * NA;
    double acc = 0.0;
    for (int j = lane; j < NA; j += 64) {
      double v = (double)row[j] * rsh[j];
      acc += v * v;
    }
    acc = wave_reduce64(acc);
    if (lane == 0) {
      double ri = rsh[i];
      xn[s * NA + i] = acc * ri * ri;
    }
  }
}

__global__ __launch_bounds__(256) void k_centers_init(const float* __restrict__ cov, const double* __restrict__ rstd,
                                                      double* __restrict__ C, InitIdx ii) {
  int w = blockIdx.x;  // 40
  int s = w / NK, k = w % NK;
  int idx = ii.v[s * NK + k];
  const float* row = cov + (size_t)s * NA * NA + (size_t)idx * NA;
  const double* rs = rstd + s * NA;
  double ri = rs[idx];
  for (int j = threadIdx.x; j < NA; j += 256)
    C[((size_t)s * NK + k) * NA + j] = (double)row[j] * ri * rs[j];
}

__global__ void k_state_init(double* pot, int* conv) {
  int t = threadIdx.x;
  if (t < NS) { pot[t] = INFINITY; conv[t] = 0; }
}

// ---------------- KMeans iteration: 2 launches, fused single cov pass ----------------
// kA: 256 blocks x 1024 thr (8 samples x 32 blocks, 32 rows/block).
// Computes assignments AND this block's partial new-center sums in one cov pass.
__global__ __launch_bounds__(1024) void k_assignA(const float* __restrict__ cov, const double* __restrict__ rstd,
                                                  const double* __restrict__ xn, const double* __restrict__ C,
                                                  const int* __restrict__ conv, int* __restrict__ ixs,
                                                  double* __restrict__ mind, double* __restrict__ pU) {
  int blk = blockIdx.x, s = blk >> 5, rblk = blk & 31;
  if (conv[s]) return;  // frozen: coherent via kernel-boundary ordering (no fences)
  __shared__ double Cs[NK][NA];  // rstd_j-scaled centers, 40 KB
  __shared__ double red16[16];
  __shared__ int bks[32];
  __shared__ double rloc[32];
  int t = threadIdx.x, lane = t & 63, wid = t >> 6;
  double rj = rstd[s * NA + t];
  double sq[NK];
#pragma unroll
  for (int k = 0; k < NK; k++) {
    double c = C[((size_t)s * NK + k) * NA + t];
    Cs[k][t] = c * rj;
    sq[k] = c * c;
  }
  double cn[NK];
#pragma unroll
  for (int k = 0; k < NK; k++) cn[k] = blk_sum_1024(sq[k], red16);
  const float* covS = cov + (size_t)s * NA * NA;
#pragma unroll
  for (int r2 = 0; r2 < 2; r2++) {
    int il = wid * 2 + r2;          // 0..31
    int i = rblk * 32 + il;
    const float* row = covS + (size_t)i * NA;
    double xi = xn[s * NA + i];
    double ri = rstd[s * NA + i];
    double a0 = 0, a1 = 0, a2 = 0, a3 = 0, a4 = 0;
#pragma unroll
    for (int c = 0; c < 16; c++) {
      int j = lane + (c << 6);
      double cv = (double)row[j];
      a0 += cv * Cs[0][j]; a1 += cv * Cs[1][j]; a2 += cv * Cs[2][j];
      a3 += cv * Cs[3][j]; a4 += cv * Cs[4][j];
    }
    a0 = wave_reduce64(a0); a1 = wave_reduce64(a1); a2 = wave_reduce64(a2);
    a3 = wave_reduce64(a3); a4 = wave_reduce64(a4);
    if (lane == 0) {
      double dots[5] = {a0, a1, a2, a3, a4};
      double best = INFINITY;
      int bk = 0;
#pragma unroll
      for (int k = 0; k < NK; k++) {
        double d = xi + cn[k] - 2.0 * ri * dots[k];
        if (d < 0.0) d = 0.0;
        if (d < best) { best = d; bk = k; }  // first-min like jnp.argmin
      }
      ixs[s * NA + i] = bk;
      mind[s * NA + i] = best;
      bks[il] = bk;
      rloc[il] = ri;
    }
  }
  __syncthreads();
  // partial center sums: thread t owns column t; ascending il -> deterministic
  double c0 = 0, c1 = 0, c2 = 0, c3 = 0, c4 = 0;
#pragma unroll
  for (int il = 0; il < 32; il++) {
    int i = rblk * 32 + il;
    double v = (double)covS[(size_t)i * NA + t] * rloc[il];  // L2-hot re-read
    int k = bks[il];
    c0 += (k == 0) ? v : 0.0;
    c1 += (k == 1) ? v : 0.0;
    c2 += (k == 2) ? v : 0.0;
    c3 += (k == 3) ? v : 0.0;
    c4 += (k == 4) ? v : 0.0;
  }
  double* p = pU + ((size_t)blk * NK) * NA;
  p[0 * NA + t] = c0; p[1 * NA + t] = c1; p[2 * NA + t] = c2;
  p[3 * NA + t] = c3; p[4 * NA + t] = c4;
}

// kB: 32 blocks x 256 thr (8 samples x 4 col-segments). Combines 32 partials
// (ascending block = ascending i: deterministic), counts, writes C; seg 0 does pot/conv.
__global__ __launch_bounds__(256) void k_updateB(const double* __restrict__ pU, const double* __restrict__ rstd,
                                                 const int* __restrict__ ixs, const double* __restrict__ mind,
                                                 double* __restrict__ C, double* __restrict__ pot,
                                                 int* __restrict__ conv) {
  int w = blockIdx.x, s = w >> 2, seg = w & 3, t = threadIdx.x;
  if (conv[s]) return;
  __shared__ double red4[4];
  double lc[NK] = {0, 0, 0, 0, 0};
#pragma unroll
  for (int q = 0; q < 4; q++) {
    int c = ixs[s * NA + q * 256 + t];
    lc[0] += (c == 0) ? 1.0 : 0.0;
    lc[1] += (c == 1) ? 1.0 : 0.0;
    lc[2] += (c == 2) ? 1.0 : 0.0;
    lc[3] += (c == 3) ? 1.0 : 0.0;
    lc[4] += (c == 4) ? 1.0 : 0.0;
  }
  double cntk[NK];
#pragma unroll
  for (int k = 0; k < NK; k++) cntk[k] = blk_sum_256(lc[k], red4);
  int j = seg * 256 + t;
  double rjj = rstd[s * NA + j];
  double* CS = C + (size_t)s * NK * NA;
#pragma unroll
  for (int k = 0; k < NK; k++) {
    double a = 0.0;
#pragma unroll
    for (int b = 0; b < 32; b++) {  // ascending b == ascending i: deterministic
      int blk = (s << 5) | b;
      a += pU[((size_t)blk * NK + k) * NA + j];
    }
    if (cntk[k] > 0.0) CS[(size_t)k * NA + j] = a * rjj / cntk[k];
    // empty cluster: keep previous center (matches jnp.where(counts>0,...))
  }
  if (seg == 0) {
    double v = mind[s * NA + t] + mind[s * NA + 256 + t] +
               mind[s * NA + 512 + t] + mind[s * NA + 768 + t];
    double p = blk_sum_256(v, red4);
    if (t == 0) {
      double prev = pot[s];
      pot[s] = p;
      if (!(fabs(p - prev) >= TOLER)) conv[s] = 1;  // freeze (while-cond fails)
    }
  }
}

// ---------------- post-processing ----------------
__global__ __launch_bounds__(256) void k_members(const int* __restrict__ ixs, int* __restrict__ g,
                                                 int* __restrict__ cnt, int* __restrict__ off5,
                                                 int* __restrict__ boff) {
  int s = blockIdx.x, t = threadIdx.x;
  __shared__ int sc[NK][256];
  __shared__ int base[NK];
  const int* ix = ixs + s * NA;
  int my[4];
  int lc[NK] = {0, 0, 0, 0, 0};
#pragma unroll
  for (int q = 0; q < 4; q++) { my[q] = ix[t * 4 + q]; lc[my[q]]++; }
#pragma unroll
  for (int k = 0; k < NK; k++) sc[k][t] = lc[k];
  __syncthreads();
  for (int off = 1; off < 256; off <<= 1) {
    int v[NK];
#pragma unroll
    for (int k = 0; k < NK; k++) v[k] = (t >= off) ? sc[k][t - off] : 0;
    __syncthreads();
#pragma unroll
    for (int k = 0; k < NK; k++) sc[k][t] += v[k];
    __syncthreads();
  }
  if (t == 0) {
    int b = 0, bo = 0;
    for (int k = 0; k < NK; k++) {
      int tot = sc[k][255];
      base[k] = b;
      cnt[s * NK + k] = tot;
      off5[s * NK + k] = b;
      boff[s * NK + k] = bo;
      b += tot;
      bo += tot * tot;
    }
  }
  __syncthreads();
  int pos[NK];
#pragma unroll
  for (int k = 0; k < NK; k++) pos[k] = base[k] + sc[k][t] - lc[k];
#pragma unroll
  for (int q = 0; q < 4; q++) {
    int k = my[q];
    int p = pos[k]++;
    g[s * NA + p] = t * 4 + q;  // stable ascending asset order within cluster
  }
}

// One-time compact gather: cluster k of sample s -> dense n x n f32 at lda=n.
__global__ __launch_bounds__(1024) void k_gatherB(const float* __restrict__ cov, const int* __restrict__ g,
                                                  const int* __restrict__ cnt, const int* __restrict__ off5,
                                                  const int* __restrict__ boff, float* __restrict__ B) {
  int w = blockIdx.x;  // 40
  int s = w / NK, k = w % NK;
  int n = cnt[s * NK + k];
  if (n == 0) return;
  int off = off5[s * NK + k];
  __shared__ int gs[NA];
  int t = threadIdx.x, lane = t & 63, wid = t >> 6;
  if (t < n) gs[t] = g[s * NA + off + t];
  __syncthreads();
  const float* covS = cov + (size_t)s * NA * NA;
  float* Bk = B + (size_t)s * NA * NA + (size_t)boff[s * NK + k];
  for (int i = wid; i < n; i += 16) {
    const float* row = covS + (size_t)gs[i] * NA;
    float* out = Bk + (size_t)i * n;
    for (int j = lane; j < n; j += 64) out[j] = row[gs[j]];
  }
}

// f64 CG on the compact block: Sigma_cc x = 1; normalize; scatter.
__global__ __launch_bounds__(1024) void k_cg_comp(const float* __restrict__ B, const int* __restrict__ g,
                                                  const int* __restrict__ cnt, const int* __restrict__ off5,
                                                  const int* __restrict__ boff, double* __restrict__ walloc) {
  int w = blockIdx.x;  // 40
  int s = w / NK, k = w % NK;
  int n = cnt[s * NK + k];
  if (n == 0) return;
  int off = off5[s * NK + k];
  const float* A = B + (size_t)s * NA * NA + (size_t)boff[s * NK + k];
  __shared__ double xv[NA], rv[NA], pv[NA], ap[NA];
  __shared__ int gs[NA];
  __shared__ double red16[16];
  int t = threadIdx.x, lane = t & 63, wid = t >> 6;
  if (t < n) {
    gs[t] = g[s * NA + off + t];
    xv[t] = 0.0; rv[t] = 1.0; pv[t] = 1.0;
  }
  double rr = (double)n;
  __syncthreads();
  for (int iter = 0; iter < 100; iter++) {
    for (int i = wid; i < n; i += 16) {
      const float* row = A + (size_t)i * n;
      double acc = 0.0;
      for (int j = lane; j < n; j += 64) acc += (double)row[j] * pv[j];
      acc = wave_reduce64(acc);
      if (lane == 0) ap[i] = acc;
    }
    __syncthreads();
    double pp = (t < n) ? pv[t] * ap[t] : 0.0;
    double pap = blk_sum_1024(pp, red16);
    double alpha = rr / pap;
    double rp = 0.0;
    if (t < n) {
      xv[t] += alpha * pv[t];
      double rn = rv[t] - alpha * ap[t];
      rv[t] = rn;
      rp = rn * rn;
    }
    double rrn = blk_sum_1024(rp, red16);
    if (rrn < 1e-20 * (double)n) break;  // rel resid 1e-10; uniform branch
    double beta = rrn / rr;
    rr = rrn;
    if (t < n) pv[t] = rv[t] + beta * pv[t];
    __syncthreads();
  }
  double dp = (t < n) ? xv[t] : 0.0;
  double denom = blk_sum_1024(dp, red16);
  if (t < n) walloc[s * NA + gs[t]] = xv[t] / denom;
}

// Fallback (ws too small for compact B): R5's full-row CG — verified PASS.
__global__ __launch_bounds__(1024) void k_cg_full(const float* __restrict__ cov,
                                                  const int* __restrict__ g, const int* __restrict__ cnt,
                                                  const int* __restrict__ off5, double* __restrict__ walloc) {
  int w = blockIdx.x;
  int s = w / NK, k = w % NK;
  int n = cnt[s * NK + k];
  if (n == 0) return;
  int off = off5[s * NK + k];
  const float* covS = cov + (size_t)s * NA * NA;
  __shared__ double pfull[NA];
  __shared__ double xv[NA], rv[NA], pv[NA], ap[NA];
  __shared__ int gs[NA];
  __shared__ double red16[16];
  int t = threadIdx.x, lane = t & 63, wid = t >> 6;
  if (t < n) {
    gs[t] = g[s * NA + off + t];
    xv[t] = 0.0; rv[t] = 1.0; pv[t] = 1.0;
  }
  double rr = (double)n;
  __syncthreads();
  for (int iter = 0; iter < 100; iter++) {
    pfull[t] = 0.0;
    __syncthreads();
    if (t < n) pfull[gs[t]] = pv[t];
    __syncthreads();
    for (int i = wid; i < n; i += 16) {
      const float* row = covS + (size_t)gs[i] * NA;
      double acc = 0.0;
#pragma unroll
      for (int c = 0; c < 16; c++) {
        int j = lane + (c << 6);
        acc += (double)row[j] * pfull[j];
      }
      acc = wave_reduce64(acc);
      if (lane == 0) ap[i] = acc;
    }
    __syncthreads();
    double pp = (t < n) ? pv[t] * ap[t] : 0.0;
    double pap = blk_sum_1024(pp, red16);
    double alpha = rr / pap;
    double rp = 0.0;
    if (t < n) {
      xv[t] += alpha * pv[t];
      double rn = rv[t] - alpha * ap[t];
      rv[t] = rn;
      rp = rn * rn;
    }
    double rrn = blk_sum_1024(rp, red16);
    if (rrn < 1e-20 * (double)n) break;
    double beta = rrn / rr;
    rr = rrn;
    if (t < n) pv[t] = rv[t] + beta * pv[t];
    __syncthreads();
  }
  double dp = (t < n) ? xv[t] : 0.0;
  double denom = blk_sum_1024(dp, red16);
  if (t < n) walloc[s * NA + gs[t]] = xv[t] / denom;
}

__global__ __launch_bounds__(256) void k_intery(const float* __restrict__ cov, const double* __restrict__ walloc,
                                                const int* __restrict__ g, const int* __restrict__ cnt,
                                                const int* __restrict__ off5, double* __restrict__ y2) {
  int w = blockIdx.x;  // 160
  int s = w / 20, rem = w % 20, k = rem / 4, seg = rem % 4;
  int n = cnt[s * NK + k], off = off5[s * NK + k];
  int t = threadIdx.x;
  __shared__ int gsl[NA];
  __shared__ double wl[NA];
  for (int i = t; i < n; i += 256) {
    int a = g[s * NA + off + i];
    gsl[i] = a;
    wl[i] = walloc[s * NA + a];
  }
  __syncthreads();
  int j = seg * 256 + t;
  const float* covS = cov + (size_t)s * NA * NA;
  double acc = 0.0;
  for (int i = 0; i < n; i++) acc += wl[i] * (double)covS[(size_t)gsl[i] * NA + j];
  y2[((size_t)s * NK + k) * NA + j] = acc;
}

__global__ __launch_bounds__(256) void k_icov(const double* __restrict__ y2, const double* __restrict__ walloc,
                                              const int* __restrict__ ixs, double* __restrict__ w_inter) {
  int s = blockIdx.x, t = threadIdx.x;
  __shared__ double red4[4];
  __shared__ double ic[NK * NK];
  for (int k = 0; k < NK; k++) {
    double p0 = 0, p1 = 0, p2 = 0, p3 = 0, p4 = 0;
    for (int j = t; j < NA; j += 256) {
      double v = y2[((size_t)s * NK + k) * NA + j] * walloc[s * NA + j];
      int c = ixs[s * NA + j];
      p0 += (c == 0) ? v : 0.0;
      p1 += (c == 1) ? v : 0.0;
      p2 += (c == 2) ? v : 0.0;
      p3 += (c == 3) ? v : 0.0;
      p4 += (c == 4) ? v : 0.0;
    }
    double q0 = blk_sum_256(p0, red4);
    double q1 = blk_sum_256(p1, red4);
    double q2 = blk_sum_256(p2, red4);
    double q3 = blk_sum_256(p3, red4);
    double q4 = blk_sum_256(p4, red4);
    if (t == 0) {
      ic[k * NK + 0] = q0; ic[k * NK + 1] = q1; ic[k * NK + 2] = q2;
      ic[k * NK + 3] = q3; ic[k * NK + 4] = q4;
    }
  }
  __syncthreads();
  if (t == 0) {
    double M[NK * NK], b[NK], z[NK];
    for (int i = 0; i < NK * NK; i++) M[i] = ic[i];
    for (int i = 0; i < NK; i++) b[i] = 1.0;
    for (int c = 0; c < NK; c++) {
      int pr = c;
      double mb = fabs(M[c * NK + c]);
      for (int r = c + 1; r < NK; r++) {
        double a = fabs(M[r * NK + c]);
        if (a > mb) { mb = a; pr = r; }
      }
      if (pr != c) {
        for (int cc = 0; cc < NK; cc++) {
          double tmp = M[c * NK + cc]; M[c * NK + cc] = M[pr * NK + cc]; M[pr * NK + cc] = tmp;
        }
        double tb = b[c]; b[c] = b[pr]; b[pr] = tb;
      }
      double piv = M[c * NK + c];
      for (int r = c + 1; r < NK; r++) {
        double f = M[r * NK + c] / piv;
        for (int cc = c; cc < NK; cc++) M[r * NK + cc] -= f * M[c * NK + cc];
        b[r] -= f * b[c];
      }
    }
    for (int r = NK - 1; r >= 0; r--) {
      double acc = b[r];
      for (int cc = r + 1; cc < NK; cc++) acc -= M[r * NK + cc] * z[cc];
      z[r] = acc / M[r * NK + r];
    }
    double ssum = z[0] + z[1] + z[2] + z[3] + z[4];
    for (int k = 0; k < NK; k++) w_inter[s * NK + k] = z[k] / ssum;
  }
}

__global__ __launch_bounds__(256) void k_final(const double* __restrict__ walloc, const double* __restrict__ w_inter,
                                               const int* __restrict__ ixs, float* __restrict__ out) {
  int gid = blockIdx.x * 256 + threadIdx.x;
  if (gid >= NS * NA) return;
  int s = gid >> 10;
  out[gid] = (float)(walloc[gid] * w_inter[s * NK + ixs[gid]]);
}

// ---------------- launch ----------------
extern "C" void kernel_launch(void* const* d_in, const int* in_sizes, int n_in,
                              void* d_out, int out_size, void* d_ws, size_t ws_size,
                              hipStream_t stream) {
  const float* cov = (const float*)d_in[0];
  float* out = (float*)d_out;
  char* ws = (char*)d_ws;
  size_t o = 0;
  auto alloc = [&](size_t bytes) {
    size_t cur = o;
    o += (bytes + 255) & ~(size_t)255;
    return cur;
  };
  double* C = (double*)(ws + alloc((size_t)NS * NK * NA * 8));
  double* y2 = (double*)(ws + alloc((size_t)NS * NK * NA * 8));
  double* pU = (double*)(ws + alloc((size_t)256 * NK * NA * 8));  // 10.5 MB partials
  double* rstd = (double*)(ws + alloc((size_t)NS * NA * 8));
  double* xn = (double*)(ws + alloc((size_t)NS * NA * 8));
  double* mind = (double*)(ws + alloc((size_t)NS * NA * 8));
  double* walloc = (double*)(ws + alloc((size_t)NS * NA * 8));
  int* ixs = (int*)(ws + alloc((size_t)NS * NA * 4));
  int* g = (int*)(ws + alloc((size_t)NS * NA * 4));
  int* cnt = (int*)(ws + alloc((size_t)NS * NK * 4));
  int* off5 = (int*)(ws + alloc((size_t)NS * NK * 4));
  int* boff = (int*)(ws + alloc((size_t)NS * NK * 4));
  int* conv = (int*)(ws + alloc((size_t)NS * 4));
  double* pot = (double*)(ws + alloc((size_t)NS * 8));
  double* w_inter = (double*)(ws + alloc((size_t)NS * NK * 8));
  size_t bcomp_off = alloc((size_t)NS * NA * NA * 4);  // 33.55 MB, guarded
  float* Bcomp = (float*)(ws + bcomp_off);
  bool use_compact = (ws_size >= o);  // launch-time constant: same graph every call
  (void)in_sizes; (void)n_in; (void)out_size;

  InitIdx ii;
  compute_init_indices(ii);  // data-independent, identical every call

  k_rstd<<<32, 256, 0, stream>>>(cov, rstd);
  k_xn<<<512, 256, 0, stream>>>(cov, rstd, xn);
  k_centers_init<<<40, 256, 0, stream>>>(cov, rstd, C, ii);
  k_state_init<<<1, 64, 0, stream>>>(pot, conv);
  for (int it = 0; it < MAXIT; it++) {
    k_assignA<<<256, 1024, 0, stream>>>(cov, rstd, xn, C, conv, ixs, mind, pU);
    k_updateB<<<32, 256, 0, stream>>>(pU, rstd, ixs, mind, C, pot, conv);
  }
  k_members<<<8, 256, 0, stream>>>(ixs, g, cnt, off5, boff);
  if (use_compact) {
    k_gatherB<<<40, 1024, 0, stream>>>(cov, g, cnt, off5, boff, Bcomp);
    k_cg_comp<<<40, 1024, 0, stream>>>(Bcomp, g, cnt, off5, boff, walloc);
  } else {
    k_cg_full<<<40, 1024, 0, stream>>>(cov, g, cnt, off5, walloc);
  }
  k_intery<<<160, 256, 0, stream>>>(cov, walloc, g, cnt, off5, y2);
  k_icov<<<8, 256, 0, stream>>>(y2, walloc, ixs, w_inter);
  k_final<<<32, 256, 0, stream>>>(walloc, w_inter, ixs, out);
}

// Round 8
// 1085.304 us; speedup vs baseline: 2.4775x; 1.1720x over previous
//
#include <hip/hip_runtime.h>
#include <stdint.h>
#include <math.h>
#include <algorithm>

#define NS 8
#define NA 1024
#define NK 5
#define MAXIT 30
#define TOLER 1e-5
#define SSTRIDE ((size_t)NA * NA + 64 * NA)  // padded per-sample Bcomp stride (floats)

// ---------------- host-side threefry-2x32 (JAX-compatible) ----------------
static inline void tf2x32(uint32_t k0, uint32_t k1, uint32_t c0, uint32_t c1,
                          uint32_t& o0, uint32_t& o1) {
  uint32_t ks2 = k0 ^ k1 ^ 0x1BD11BDAu;
  uint32_t x0 = c0 + k0, x1 = c1 + k1;
  auto rot = [](uint32_t x, int r) { return (x << r) | (x >> (32 - r)); };
  auto R4 = [&](int r0, int r1, int r2, int r3) {
    x0 += x1; x1 = rot(x1, r0); x1 ^= x0;
    x0 += x1; x1 = rot(x1, r1); x1 ^= x0;
    x0 += x1; x1 = rot(x1, r2); x1 ^= x0;
    x0 += x1; x1 = rot(x1, r3); x1 ^= x0;
  };
  R4(13, 15, 26, 6);  x0 += k1;  x1 += ks2 + 1u;
  R4(17, 29, 16, 24); x0 += ks2; x1 += k0 + 2u;
  R4(13, 15, 26, 6);  x0 += k0;  x1 += k1 + 3u;
  R4(17, 29, 16, 24); x0 += k1;  x1 += ks2 + 4u;
  R4(13, 15, 26, 6);  x0 += ks2; x1 += k0 + 5u;
  o0 = x0; o1 = x1;
}

struct InitIdx { int v[NS * NK]; };

// jax_threefry_partitionable=True semantics (verified R3/R5/R6/R7: PASS)
static void compute_init_indices(InitIdx& out) {
  const uint32_t rk0 = 0, rk1 = 42;
  for (int s = 0; s < NS; s++) {
    uint32_t k0, k1;
    tf2x32(rk0, rk1, 0u, (uint32_t)s, k0, k1);
    uint32_t sk0, sk1;
    tf2x32(k0, k1, 0u, 1u, sk0, sk1);
    uint32_t bits[NA];
    for (int i = 0; i < NA; i++) {
      uint32_t b0, b1;
      tf2x32(sk0, sk1, 0u, (uint32_t)i, b0, b1);
      bits[i] = b0 ^ b1;
    }
    int idx[NA];
    for (int i = 0; i < NA; i++) idx[i] = i;
    std::stable_sort(idx, idx + NA, [&](int x, int y) { return bits[x] < bits[y]; });
    for (int c = 0; c < NK; c++) out.v[s * NK + c] = idx[c];
  }
}

// ---------------- device helpers ----------------
__device__ __forceinline__ double wave_reduce64(double v) {
#pragma unroll
  for (int m = 32; m > 0; m >>= 1) v += __shfl_xor(v, m, 64);
  return v;
}

__device__ __forceinline__ double blk_sum_1024(double v, double* red16) {
  double w = wave_reduce64(v);
  if ((threadIdx.x & 63) == 0) red16[threadIdx.x >> 6] = w;
  __syncthreads();
  double tot = 0.0;
#pragma unroll
  for (int i = 0; i < 16; i++) tot += red16[i];
  __syncthreads();
  return tot;
}

__device__ __forceinline__ double blk_sum_256(double v, double* red4) {
  double w = wave_reduce64(v);
  if ((threadIdx.x & 63) == 0) red4[threadIdx.x >> 6] = w;
  __syncthreads();
  double tot = red4[0] + red4[1] + red4[2] + red4[3];
  __syncthreads();
  return tot;
}

// Fused dual block-sum (1024 thr): one LDS pass, one barrier pair, deterministic.
__device__ __forceinline__ void blk_sum2_1024(double a, double b, double* redA, double* redB,
                                              double& ra, double& rb) {
#pragma unroll
  for (int m = 32; m > 0; m >>= 1) {
    a += __shfl_xor(a, m, 64);
    b += __shfl_xor(b, m, 64);
  }
  if ((threadIdx.x & 63) == 0) {
    redA[threadIdx.x >> 6] = a;
    redB[threadIdx.x >> 6] = b;
  }
  __syncthreads();
  ra = 0.0; rb = 0.0;
#pragma unroll
  for (int i = 0; i < 16; i++) { ra += redA[i]; rb += redB[i]; }
  __syncthreads();
}

// ---------------- pre-kernels ----------------
__global__ __launch_bounds__(256) void k_rstd(const float* __restrict__ cov, double* __restrict__ rstd) {
  int gid = blockIdx.x * 256 + threadIdx.x;
  if (gid >= NS * NA) return;
  int s = gid >> 10, a = gid & 1023;
  double d = (double)cov[(size_t)s * NA * NA + (size_t)a * NA + a];
  rstd[gid] = 1.0 / sqrt(d);
}

__global__ __launch_bounds__(256) void k_xn(const float* __restrict__ cov, const double* __restrict__ rstd,
                                            double* __restrict__ xn) {
  int w = blockIdx.x;  // 512
  int s = w >> 6;
  __shared__ double rsh[NA];
  for (int j = threadIdx.x; j < NA; j += 256) rsh[j] = rstd[s * NA + j];
  __syncthreads();
  int lane = threadIdx.x & 63, wave = threadIdx.x >> 6;
  const float* covS = cov + (size_t)s * NA * NA;
  for (int q = 0; q < 4; q++) {
    int i = (w & 63) * 16 + wave * 4 + q;
    const float* row = covS + (size_t)i * NA;
    double acc = 0.0;
    for (int j = lane; j < NA; j += 64) {
      double v = (double)row[j] * rsh[j];
      acc += v * v;
    }
    acc = wave_reduce64(acc);
    if (lane == 0) {
      double ri = rsh[i];
      xn[s * NA + i] = acc * ri * ri;
    }
  }
}

__global__ __launch_bounds__(256) void k_centers_init(const float* __restrict__ cov, const double* __restrict__ rstd,
                                                      double* __restrict__ C, InitIdx ii) {
  int w = blockIdx.x;  // 40
  int s = w / NK, k = w % NK;
  int idx = ii.v[s * NK + k];
  const float* row = cov + (size_t)s * NA * NA + (size_t)idx * NA;
  const double* rs = rstd + s * NA;
  double ri = rs[idx];
  for (int j = threadIdx.x; j < NA; j += 256)
    C[((size_t)s * NK + k) * NA + j] = (double)row[j] * ri * rs[j];
}

__global__ void k_state_init(double* pot, int* conv) {
  int t = threadIdx.x;
  if (t < NS) { pot[t] = INFINITY; conv[t] = 0; }
}

// ---------------- KMeans iteration: 2 launches, fused single cov pass ----------------
__global__ __launch_bounds__(1024) void k_assignA(const float* __restrict__ cov, const double* __restrict__ rstd,
                                                  const double* __restrict__ xn, const double* __restrict__ C,
                                                  const int* __restrict__ conv, int* __restrict__ ixs,
                                                  double* __restrict__ mind, double* __restrict__ pU) {
  int blk = blockIdx.x, s = blk >> 5, rblk = blk & 31;
  if (conv[s]) return;  // frozen: coherent via kernel-boundary ordering
  __shared__ double Cs[NK][NA];  // rstd_j-scaled centers, 40 KB
  __shared__ double red16[16];
  __shared__ int bks[32];
  __shared__ double rloc[32];
  int t = threadIdx.x, lane = t & 63, wid = t >> 6;
  double rj = rstd[s * NA + t];
  double sq[NK];
#pragma unroll
  for (int k = 0; k < NK; k++) {
    double c = C[((size_t)s * NK + k) * NA + t];
    Cs[k][t] = c * rj;
    sq[k] = c * c;
  }
  double cn[NK];
#pragma unroll
  for (int k = 0; k < NK; k++) cn[k] = blk_sum_1024(sq[k], red16);
  const float* covS = cov + (size_t)s * NA * NA;
#pragma unroll
  for (int r2 = 0; r2 < 2; r2++) {
    int il = wid * 2 + r2;          // 0..31
    int i = rblk * 32 + il;
    const float* row = covS + (size_t)i * NA;
    double xi = xn[s * NA + i];
    double ri = rstd[s * NA + i];
    double a0 = 0, a1 = 0, a2 = 0, a3 = 0, a4 = 0;
#pragma unroll
    for (int c = 0; c < 16; c++) {
      int j = lane + (c << 6);
      double cv = (double)row[j];
      a0 += cv * Cs[0][j]; a1 += cv * Cs[1][j]; a2 += cv * Cs[2][j];
      a3 += cv * Cs[3][j]; a4 += cv * Cs[4][j];
    }
    a0 = wave_reduce64(a0); a1 = wave_reduce64(a1); a2 = wave_reduce64(a2);
    a3 = wave_reduce64(a3); a4 = wave_reduce64(a4);
    if (lane == 0) {
      double dots[5] = {a0, a1, a2, a3, a4};
      double best = INFINITY;
      int bk = 0;
#pragma unroll
      for (int k = 0; k < NK; k++) {
        double d = xi + cn[k] - 2.0 * ri * dots[k];
        if (d < 0.0) d = 0.0;
        if (d < best) { best = d; bk = k; }  // first-min like jnp.argmin
      }
      ixs[s * NA + i] = bk;
      mind[s * NA + i] = best;
      bks[il] = bk;
      rloc[il] = ri;
    }
  }
  __syncthreads();
  // partial center sums: thread t owns column t; ascending il -> deterministic
  double c0 = 0, c1 = 0, c2 = 0, c3 = 0, c4 = 0;
#pragma unroll
  for (int il = 0; il < 32; il++) {
    int i = rblk * 32 + il;
    double v = (double)covS[(size_t)i * NA + t] * rloc[il];  // L2-hot re-read
    int k = bks[il];
    c0 += (k == 0) ? v : 0.0;
    c1 += (k == 1) ? v : 0.0;
    c2 += (k == 2) ? v : 0.0;
    c3 += (k == 3) ? v : 0.0;
    c4 += (k == 4) ? v : 0.0;
  }
  double* p = pU + ((size_t)blk * NK) * NA;
  p[0 * NA + t] = c0; p[1 * NA + t] = c1; p[2 * NA + t] = c2;
  p[3 * NA + t] = c3; p[4 * NA + t] = c4;
}

__global__ __launch_bounds__(256) void k_updateB(const double* __restrict__ pU, const double* __restrict__ rstd,
                                                 const int* __restrict__ ixs, const double* __restrict__ mind,
                                                 double* __restrict__ C, double* __restrict__ pot,
                                                 int* __restrict__ conv) {
  int w = blockIdx.x, s = w >> 2, seg = w & 3, t = threadIdx.x;
  if (conv[s]) return;
  __shared__ double red4[4];
  double lc[NK] = {0, 0, 0, 0, 0};
#pragma unroll
  for (int q = 0; q < 4; q++) {
    int c = ixs[s * NA + q * 256 + t];
    lc[0] += (c == 0) ? 1.0 : 0.0;
    lc[1] += (c == 1) ? 1.0 : 0.0;
    lc[2] += (c == 2) ? 1.0 : 0.0;
    lc[3] += (c == 3) ? 1.0 : 0.0;
    lc[4] += (c == 4) ? 1.0 : 0.0;
  }
  double cntk[NK];
#pragma unroll
  for (int k = 0; k < NK; k++) cntk[k] = blk_sum_256(lc[k], red4);
  int j = seg * 256 + t;
  double rjj = rstd[s * NA + j];
  double* CS = C + (size_t)s * NK * NA;
#pragma unroll
  for (int k = 0; k < NK; k++) {
    double a = 0.0;
#pragma unroll
    for (int b = 0; b < 32; b++) {  // ascending b == ascending i: deterministic
      int blk = (s << 5) | b;
      a += pU[((size_t)blk * NK + k) * NA + j];
    }
    if (cntk[k] > 0.0) CS[(size_t)k * NA + j] = a * rjj / cntk[k];
    // empty cluster: keep previous center
  }
  if (seg == 0) {
    double v = mind[s * NA + t] + mind[s * NA + 256 + t] +
               mind[s * NA + 512 + t] + mind[s * NA + 768 + t];
    double p = blk_sum_256(v, red4);
    if (t == 0) {
      double prev = pot[s];
      pot[s] = p;
      if (!(fabs(p - prev) >= TOLER)) conv[s] = 1;  // freeze (while-cond fails)
    }
  }
}

// ---------------- post-processing ----------------
__global__ __launch_bounds__(256) void k_members(const int* __restrict__ ixs, int* __restrict__ g,
                                                 int* __restrict__ cnt, int* __restrict__ off5,
                                                 int* __restrict__ boff) {
  int s = blockIdx.x, t = threadIdx.x;
  __shared__ int sc[NK][256];
  __shared__ int base[NK];
  const int* ix = ixs + s * NA;
  int my[4];
  int lc[NK] = {0, 0, 0, 0, 0};
#pragma unroll
  for (int q = 0; q < 4; q++) { my[q] = ix[t * 4 + q]; lc[my[q]]++; }
#pragma unroll
  for (int k = 0; k < NK; k++) sc[k][t] = lc[k];
  __syncthreads();
  for (int off = 1; off < 256; off <<= 1) {
    int v[NK];
#pragma unroll
    for (int k = 0; k < NK; k++) v[k] = (t >= off) ? sc[k][t - off] : 0;
    __syncthreads();
#pragma unroll
    for (int k = 0; k < NK; k++) sc[k][t] += v[k];
    __syncthreads();
  }
  if (t == 0) {
    int b = 0, bo = 0;
    for (int k = 0; k < NK; k++) {
      int tot = sc[k][255];
      base[k] = b;
      cnt[s * NK + k] = tot;
      off5[s * NK + k] = b;
      boff[s * NK + k] = bo;
      b += tot;
      bo += tot * ((tot + 63) & ~63);  // padded: lda = align64(n)
    }
  }
  __syncthreads();
  int pos[NK];
#pragma unroll
  for (int k = 0; k < NK; k++) pos[k] = base[k] + sc[k][t] - lc[k];
#pragma unroll
  for (int q = 0; q < 4; q++) {
    int k = my[q];
    int p = pos[k]++;
    g[s * NA + p] = t * 4 + q;  // stable ascending asset order within cluster
  }
}

// Compact gather, PADDED: lda = align64(n), zero-filled pad (exact dot contributions).
__global__ __launch_bounds__(1024) void k_gatherB(const float* __restrict__ cov, const int* __restrict__ g,
                                                  const int* __restrict__ cnt, const int* __restrict__ off5,
                                                  const int* __restrict__ boff, float* __restrict__ B) {
  int w = blockIdx.x;  // 40
  int s = w / NK, k = w % NK;
  int n = cnt[s * NK + k];
  if (n == 0) return;
  int lda = (n + 63) & ~63;
  int off = off5[s * NK + k];
  __shared__ int gs[NA];
  int t = threadIdx.x, lane = t & 63, wid = t >> 6;
  if (t < n) gs[t] = g[s * NA + off + t];
  __syncthreads();
  const float* covS = cov + (size_t)s * NA * NA;
  float* Bk = B + (size_t)s * SSTRIDE + (size_t)boff[s * NK + k];
  for (int i = wid; i < n; i += 16) {
    const float* row = covS + (size_t)gs[i] * NA;
    float* out = Bk + (size_t)i * lda;
    for (int j = lane; j < lda; j += 64) out[j] = (j < n) ? row[gs[j]] : 0.0f;
  }
}

// Chronopoulos-Gear CG (single fused reduction/iter) on padded block, f64 state,
// float4 row loads + b128 LDS reads. Solves Sigma_cc x = 1; normalize; scatter.
__global__ __launch_bounds__(1024) void k_cg_comp(const float* __restrict__ B, const int* __restrict__ g,
                                                  const int* __restrict__ cnt, const int* __restrict__ off5,
                                                  const int* __restrict__ boff, double* __restrict__ walloc) {
  int w = blockIdx.x;  // 40
  int s = w / NK, k = w % NK;
  int n = cnt[s * NK + k];
  if (n == 0) return;
  int lda = (n + 63) & ~63;
  int off = off5[s * NK + k];
  const float* A = B + (size_t)s * SSTRIDE + (size_t)boff[s * NK + k];
  __shared__ __align__(16) double xv[NA], rv[NA], pv[NA], sv[NA], wv[NA];
  __shared__ int gs[NA];
  __shared__ double redA[16], redB[16];
  int t = threadIdx.x, lane = t & 63, wid = t >> 6;
  const double2* rv2 = (const double2*)rv;
  if (t < n) gs[t] = g[s * NA + off + t];
  rv[t] = (t < n) ? 1.0 : 0.0;  // pad zero: float4 chunks read rv up to lda
  if (t < n) xv[t] = 0.0;
  __syncthreads();
  // w = A r
  for (int i = wid; i < n; i += 16) {
    const float4* rowv = (const float4*)(A + (size_t)i * lda);
    double acc = 0.0;
    for (int c = 0; c < lda; c += 256) {
      float4 av = rowv[(c >> 2) + lane];
      int jb = (c + (lane << 2)) >> 1;
      double2 r01 = rv2[jb];
      double2 r23 = rv2[jb + 1];
      acc += (double)av.x * r01.x + (double)av.y * r01.y +
             (double)av.z * r23.x + (double)av.w * r23.y;
    }
    acc = wave_reduce64(acc);
    if (lane == 0) wv[i] = acc;
  }
  __syncthreads();
  double gam = (double)n;  // (r,r) with r=1
  double d1, d2;
  blk_sum2_1024((t < n) ? wv[t] : 0.0, 0.0, redA, redB, d1, d2);  // delta=(w,r), r=1
  double alpha = gam / d1;
  if (t < n) { pv[t] = rv[t]; sv[t] = wv[t]; }
  const double tol = 1e-12 * (double)n;  // rel resid 1e-6: err ~ kappa*1e-6*|w| << floor
  for (int iter = 0; iter < 60; iter++) {
    if (t < n) {
      xv[t] += alpha * pv[t];
      rv[t] -= alpha * sv[t];
    }
    __syncthreads();
    // w = A r
    for (int i = wid; i < n; i += 16) {
      const float4* rowv = (const float4*)(A + (size_t)i * lda);
      double acc = 0.0;
      for (int c = 0; c < lda; c += 256) {
        float4 av = rowv[(c >> 2) + lane];
        int jb = (c + (lane << 2)) >> 1;
        double2 r01 = rv2[jb];
        double2 r23 = rv2[jb + 1];
        acc += (double)av.x * r01.x + (double)av.y * r01.y +
               (double)av.z * r23.x + (double)av.w * r23.y;
      }
      acc = wave_reduce64(acc);
      if (lane == 0) wv[i] = acc;
    }
    __syncthreads();
    double g1 = 0.0, g2 = 0.0;
    if (t < n) {
      double rt = rv[t];
      g1 = rt * rt;
      g2 = rt * wv[t];
    }
    double gamn, delt;
    blk_sum2_1024(g1, g2, redA, redB, gamn, delt);
    if (gamn < tol) break;  // uniform across block
    double beta = gamn / gam;
    alpha = gamn / (delt - beta * gamn / alpha);
    gam = gamn;
    if (t < n) {
      pv[t] = rv[t] + beta * pv[t];
      sv[t] = wv[t] + beta * sv[t];
    }
    // no extra sync: next x/r update is thread-local; matvec sync covers rv
  }
  double dp = (t < n) ? xv[t] : 0.0;
  double d3, d4;
  blk_sum2_1024(dp, 0.0, redA, redB, d3, d4);
  if (t < n) walloc[s * NA + gs[t]] = xv[t] / d3;
}

// Fallback (ws too small for compact B): R5's full-row CG — verified PASS.
__global__ __launch_bounds__(1024) void k_cg_full(const float* __restrict__ cov,
                                                  const int* __restrict__ g, const int* __restrict__ cnt,
                                                  const int* __restrict__ off5, double* __restrict__ walloc) {
  int w = blockIdx.x;
  int s = w / NK, k = w % NK;
  int n = cnt[s * NK + k];
  if (n == 0) return;
  int off = off5[s * NK + k];
  const float* covS = cov + (size_t)s * NA * NA;
  __shared__ double pfull[NA];
  __shared__ double xv[NA], rv[NA], pv[NA], ap[NA];
  __shared__ int gs[NA];
  __shared__ double red16[16];
  int t = threadIdx.x, lane = t & 63, wid = t >> 6;
  if (t < n) {
    gs[t] = g[s * NA + off + t];
    xv[t] = 0.0; rv[t] = 1.0; pv[t] = 1.0;
  }
  double rr = (double)n;
  __syncthreads();
  for (int iter = 0; iter < 100; iter++) {
    pfull[t] = 0.0;
    __syncthreads();
    if (t < n) pfull[gs[t]] = pv[t];
    __syncthreads();
    for (int i = wid; i < n; i += 16) {
      const float* row = covS + (size_t)gs[i] * NA;
      double acc = 0.0;
#pragma unroll
      for (int c = 0; c < 16; c++) {
        int j = lane + (c << 6);
        acc += (double)row[j] * pfull[j];
      }
      acc = wave_reduce64(acc);
      if (lane == 0) ap[i] = acc;
    }
    __syncthreads();
    double pp = (t < n) ? pv[t] * ap[t] : 0.0;
    double pap = blk_sum_1024(pp, red16);
    double alpha = rr / pap;
    double rp = 0.0;
    if (t < n) {
      xv[t] += alpha * pv[t];
      double rn = rv[t] - alpha * ap[t];
      rv[t] = rn;
      rp = rn * rn;
    }
    double rrn = blk_sum_1024(rp, red16);
    if (rrn < 1e-20 * (double)n) break;
    double beta = rrn / rr;
    rr = rrn;
    if (t < n) pv[t] = rv[t] + beta * pv[t];
    __syncthreads();
  }
  double dp = (t < n) ? xv[t] : 0.0;
  double denom = blk_sum_1024(dp, red16);
  if (t < n) walloc[s * NA + gs[t]] = xv[t] / denom;
}

__global__ __launch_bounds__(256) void k_intery(const float* __restrict__ cov, const double* __restrict__ walloc,
                                                const int* __restrict__ g, const int* __restrict__ cnt,
                                                const int* __restrict__ off5, double* __restrict__ y2) {
  int w = blockIdx.x;  // 160
  int s = w / 20, rem = w % 20, k = rem / 4, seg = rem % 4;
  int n = cnt[s * NK + k], off = off5[s * NK + k];
  int t = threadIdx.x;
  __shared__ int gsl[NA];
  __shared__ double wl[NA];
  for (int i = t; i < n; i += 256) {
    int a = g[s * NA + off + i];
    gsl[i] = a;
    wl[i] = walloc[s * NA + a];
  }
  __syncthreads();
  int j = seg * 256 + t;
  const float* covS = cov + (size_t)s * NA * NA;
  double acc = 0.0;
  for (int i = 0; i < n; i++) acc += wl[i] * (double)covS[(size_t)gsl[i] * NA + j];
  y2[((size_t)s * NK + k) * NA + j] = acc;
}

__global__ __launch_bounds__(256) void k_icov(const double* __restrict__ y2, const double* __restrict__ walloc,
                                              const int* __restrict__ ixs, double* __restrict__ w_inter) {
  int s = blockIdx.x, t = threadIdx.x;
  __shared__ double red4[4];
  __shared__ double ic[NK * NK];
  for (int k = 0; k < NK; k++) {
    double p0 = 0, p1 = 0, p2 = 0, p3 = 0, p4 = 0;
    for (int j = t; j < NA; j += 256) {
      double v = y2[((size_t)s * NK + k) * NA + j] * walloc[s * NA + j];
      int c = ixs[s * NA + j];
      p0 += (c == 0) ? v : 0.0;
      p1 += (c == 1) ? v : 0.0;
      p2 += (c == 2) ? v : 0.0;
      p3 += (c == 3) ? v : 0.0;
      p4 += (c == 4) ? v : 0.0;
    }
    double q0 = blk_sum_256(p0, red4);
    double q1 = blk_sum_256(p1, red4);
    double q2 = blk_sum_256(p2, red4);
    double q3 = blk_sum_256(p3, red4);
    double q4 = blk_sum_256(p4, red4);
    if (t == 0) {
      ic[k * NK + 0] = q0; ic[k * NK + 1] = q1; ic[k * NK + 2] = q2;
      ic[k * NK + 3] = q3; ic[k * NK + 4] = q4;
    }
  }
  __syncthreads();
  if (t == 0) {
    double M[NK * NK], b[NK], z[NK];
    for (int i = 0; i < NK * NK; i++) M[i] = ic[i];
    for (int i = 0; i < NK; i++) b[i] = 1.0;
    for (int c = 0; c < NK; c++) {
      int pr = c;
      double mb = fabs(M[c * NK + c]);
      for (int r = c + 1; r < NK; r++) {
        double a = fabs(M[r * NK + c]);
        if (a > mb) { mb = a; pr = r; }
      }
      if (pr != c) {
        for (int cc = 0; cc < NK; cc++) {
          double tmp = M[c * NK + cc]; M[c * NK + cc] = M[pr * NK + cc]; M[pr * NK + cc] = tmp;
        }
        double tb = b[c]; b[c] = b[pr]; b[pr] = tb;
      }
      double piv = M[c * NK + c];
      for (int r = c + 1; r < NK; r++) {
        double f = M[r * NK + c] / piv;
        for (int cc = c; cc < NK; cc++) M[r * NK + cc] -= f * M[c * NK + cc];
        b[r] -= f * b[c];
      }
    }
    for (int r = NK - 1; r >= 0; r--) {
      double acc = b[r];
      for (int cc = r + 1; cc < NK; cc++) acc -= M[r * NK + cc] * z[cc];
      z[r] = acc / M[r * NK + r];
    }
    double ssum = z[0] + z[1] + z[2] + z[3] + z[4];
    for (int k = 0; k < NK; k++) w_inter[s * NK + k] = z[k] / ssum;
  }
}

__global__ __launch_bounds__(256) void k_final(const double* __restrict__ walloc, const double* __restrict__ w_inter,
                                               const int* __restrict__ ixs, float* __restrict__ out) {
  int gid = blockIdx.x * 256 + threadIdx.x;
  if (gid >= NS * NA) return;
  int s = gid >> 10;
  out[gid] = (float)(walloc[gid] * w_inter[s * NK + ixs[gid]]);
}

// ---------------- launch ----------------
extern "C" void kernel_launch(void* const* d_in, const int* in_sizes, int n_in,
                              void* d_out, int out_size, void* d_ws, size_t ws_size,
                              hipStream_t stream) {
  const float* cov = (const float*)d_in[0];
  float* out = (float*)d_out;
  char* ws = (char*)d_ws;
  size_t o = 0;
  auto alloc = [&](size_t bytes) {
    size_t cur = o;
    o += (bytes + 255) & ~(size_t)255;
    return cur;
  };
  double* C = (double*)(ws + alloc((size_t)NS * NK * NA * 8));
  double* y2 = (double*)(ws + alloc((size_t)NS * NK * NA * 8));
  double* pU = (double*)(ws + alloc((size_t)256 * NK * NA * 8));  // 10.5 MB partials
  double* rstd = (double*)(ws + alloc((size_t)NS * NA * 8));
  double* xn = (double*)(ws + alloc((size_t)NS * NA * 8));
  double* mind = (double*)(ws + alloc((size_t)NS * NA * 8));
  double* walloc = (double*)(ws + alloc((size_t)NS * NA * 8));
  int* ixs = (int*)(ws + alloc((size_t)NS * NA * 4));
  int* g = (int*)(ws + alloc((size_t)NS * NA * 4));
  int* cnt = (int*)(ws + alloc((size_t)NS * NK * 4));
  int* off5 = (int*)(ws + alloc((size_t)NS * NK * 4));
  int* boff = (int*)(ws + alloc((size_t)NS * NK * 4));
  int* conv = (int*)(ws + alloc((size_t)NS * 4));
  double* pot = (double*)(ws + alloc((size_t)NS * 8));
  double* w_inter = (double*)(ws + alloc((size_t)NS * NK * 8));
  size_t bcomp_off = alloc(NS * SSTRIDE * 4);  // 35.7 MB padded blocks, guarded
  float* Bcomp = (float*)(ws + bcomp_off);
  bool use_compact = (ws_size >= o);  // launch-time constant: same graph every call
  (void)in_sizes; (void)n_in; (void)out_size;

  InitIdx ii;
  compute_init_indices(ii);  // data-independent, identical every call

  k_rstd<<<32, 256, 0, stream>>>(cov, rstd);
  k_xn<<<512, 256, 0, stream>>>(cov, rstd, xn);
  k_centers_init<<<40, 256, 0, stream>>>(cov, rstd, C, ii);
  k_state_init<<<1, 64, 0, stream>>>(pot, conv);
  for (int it = 0; it < MAXIT; it++) {
    k_assignA<<<256, 1024, 0, stream>>>(cov, rstd, xn, C, conv, ixs, mind, pU);
    k_updateB<<<32, 256, 0, stream>>>(pU, rstd, ixs, mind, C, pot, conv);
  }
  k_members<<<8, 256, 0, stream>>>(ixs, g, cnt, off5, boff);
  if (use_compact) {
    k_gatherB<<<40, 1024, 0, stream>>>(cov, g, cnt, off5, boff, Bcomp);
    k_cg_comp<<<40, 1024, 0, stream>>>(Bcomp, g, cnt, off5, boff, walloc);
  } else {
    k_cg_full<<<40, 1024, 0, stream>>>(cov, g, cnt, off5, walloc);
  }
  k_intery<<<160, 256, 0, stream>>>(cov, walloc, g, cnt, off5, y2);
  k_icov<<<8, 256, 0, stream>>>(y2, walloc, ixs, w_inter);
  k_final<<<32, 256, 0, stream>>>(walloc, w_inter, ixs, out);
}

// Round 9
// 1067.995 us; speedup vs baseline: 2.5176x; 1.0162x over previous
//
#include <hip/hip_runtime.h>
#include <stdint.h>
#include <math.h>
#include <algorithm>

#define NS 8
#define NA 1024
#define NK 5
#define MAXIT 30
#define TOLER 1e-5
#define SSTRIDE ((size_t)NA * NA + 64 * NA)  // padded per-sample Bcomp stride (floats)

// ---------------- host-side threefry-2x32 (JAX-compatible) ----------------
static inline void tf2x32(uint32_t k0, uint32_t k1, uint32_t c0, uint32_t c1,
                          uint32_t& o0, uint32_t& o1) {
  uint32_t ks2 = k0 ^ k1 ^ 0x1BD11BDAu;
  uint32_t x0 = c0 + k0, x1 = c1 + k1;
  auto rot = [](uint32_t x, int r) { return (x << r) | (x >> (32 - r)); };
  auto R4 = [&](int r0, int r1, int r2, int r3) {
    x0 += x1; x1 = rot(x1, r0); x1 ^= x0;
    x0 += x1; x1 = rot(x1, r1); x1 ^= x0;
    x0 += x1; x1 = rot(x1, r2); x1 ^= x0;
    x0 += x1; x1 = rot(x1, r3); x1 ^= x0;
  };
  R4(13, 15, 26, 6);  x0 += k1;  x1 += ks2 + 1u;
  R4(17, 29, 16, 24); x0 += ks2; x1 += k0 + 2u;
  R4(13, 15, 26, 6);  x0 += k0;  x1 += k1 + 3u;
  R4(17, 29, 16, 24); x0 += k1;  x1 += ks2 + 4u;
  R4(13, 15, 26, 6);  x0 += ks2; x1 += k0 + 5u;
  o0 = x0; o1 = x1;
}

struct InitIdx { int v[NS * NK]; };

// jax_threefry_partitionable=True semantics (verified R3/R5-R8: PASS)
static void compute_init_indices(InitIdx& out) {
  const uint32_t rk0 = 0, rk1 = 42;
  for (int s = 0; s < NS; s++) {
    uint32_t k0, k1;
    tf2x32(rk0, rk1, 0u, (uint32_t)s, k0, k1);
    uint32_t sk0, sk1;
    tf2x32(k0, k1, 0u, 1u, sk0, sk1);
    uint32_t bits[NA];
    for (int i = 0; i < NA; i++) {
      uint32_t b0, b1;
      tf2x32(sk0, sk1, 0u, (uint32_t)i, b0, b1);
      bits[i] = b0 ^ b1;
    }
    int idx[NA];
    for (int i = 0; i < NA; i++) idx[i] = i;
    std::stable_sort(idx, idx + NA, [&](int x, int y) { return bits[x] < bits[y]; });
    for (int c = 0; c < NK; c++) out.v[s * NK + c] = idx[c];
  }
}

// ---------------- device helpers ----------------
__device__ __forceinline__ double wave_reduce64(double v) {
#pragma unroll
  for (int m = 32; m > 0; m >>= 1) v += __shfl_xor(v, m, 64);
  return v;
}

__device__ __forceinline__ double blk_sum_1024(double v, double* red16) {
  double w = wave_reduce64(v);
  if ((threadIdx.x & 63) == 0) red16[threadIdx.x >> 6] = w;
  __syncthreads();
  double tot = 0.0;
#pragma unroll
  for (int i = 0; i < 16; i++) tot += red16[i];
  __syncthreads();
  return tot;
}

__device__ __forceinline__ double blk_sum_256(double v, double* red4) {
  double w = wave_reduce64(v);
  if ((threadIdx.x & 63) == 0) red4[threadIdx.x >> 6] = w;
  __syncthreads();
  double tot = red4[0] + red4[1] + red4[2] + red4[3];
  __syncthreads();
  return tot;
}

// Fused dual block-sum (1024 thr): one LDS pass, one barrier pair, deterministic.
__device__ __forceinline__ void blk_sum2_1024(double a, double b, double* redA, double* redB,
                                              double& ra, double& rb) {
#pragma unroll
  for (int m = 32; m > 0; m >>= 1) {
    a += __shfl_xor(a, m, 64);
    b += __shfl_xor(b, m, 64);
  }
  if ((threadIdx.x & 63) == 0) {
    redA[threadIdx.x >> 6] = a;
    redB[threadIdx.x >> 6] = b;
  }
  __syncthreads();
  ra = 0.0; rb = 0.0;
#pragma unroll
  for (int i = 0; i < 16; i++) { ra += redA[i]; rb += redB[i]; }
  __syncthreads();
}

// ---------------- fused pre-kernel: xn + centers_init + rstd array + state ----------------
// blocks 0..511: xn (inline rstd); 512..551: centers_init; 552: rstd[]+pot+conv.
__global__ __launch_bounds__(256) void k_pre(const float* __restrict__ cov, double* __restrict__ rstd,
                                             double* __restrict__ xn, double* __restrict__ C,
                                             InitIdx ii, double* __restrict__ pot, int* __restrict__ conv) {
  int w = blockIdx.x;
  if (w < 512) {
    int s = w >> 6;
    __shared__ double rsh[NA];
    const float* covS = cov + (size_t)s * NA * NA;
    for (int j = threadIdx.x; j < NA; j += 256)
      rsh[j] = 1.0 / sqrt((double)covS[(size_t)j * NA + j]);
    __syncthreads();
    int lane = threadIdx.x & 63, wave = threadIdx.x >> 6;
    for (int q = 0; q < 4; q++) {
      int i = (w & 63) * 16 + wave * 4 + q;
      const float* row = covS + (size_t)i * NA;
      double acc = 0.0;
      for (int j = lane; j < NA; j += 64) {
        double v = (double)row[j] * rsh[j];
        acc += v * v;
      }
      acc = wave_reduce64(acc);
      if (lane == 0) {
        double ri = rsh[i];
        xn[s * NA + i] = acc * ri * ri;
      }
    }
  } else if (w < 552) {
    int w2 = w - 512;
    int s = w2 / NK, k = w2 % NK;
    int idx = ii.v[s * NK + k];
    const float* covS = cov + (size_t)s * NA * NA;
    double ri = 1.0 / sqrt((double)covS[(size_t)idx * NA + idx]);
    const float* row = covS + (size_t)idx * NA;
    for (int j = threadIdx.x; j < NA; j += 256) {
      double rj = 1.0 / sqrt((double)covS[(size_t)j * NA + j]);
      C[((size_t)s * NK + k) * NA + j] = (double)row[j] * ri * rj;
    }
  } else {
    int t = threadIdx.x;
    for (int gid = t; gid < NS * NA; gid += 256) {
      int s = gid >> 10, a = gid & 1023;
      rstd[gid] = 1.0 / sqrt((double)cov[(size_t)s * NA * NA + (size_t)a * NA + a]);
    }
    if (t < NS) { pot[t] = INFINITY; conv[t] = 0; }
  }
}

// ---------------- KMeans iteration: 2 launches, fused single cov pass ----------------
__global__ __launch_bounds__(1024) void k_assignA(const float* __restrict__ cov, const double* __restrict__ rstd,
                                                  const double* __restrict__ xn, const double* __restrict__ C,
                                                  const int* __restrict__ conv, int* __restrict__ ixs,
                                                  double* __restrict__ mind, double* __restrict__ pU) {
  int blk = blockIdx.x, s = blk >> 5, rblk = blk & 31;
  if (conv[s]) return;  // frozen: coherent via kernel-boundary ordering
  __shared__ double Cs[NK][NA];  // rstd_j-scaled centers, 40 KB
  __shared__ double red16[16];
  __shared__ int bks[32];
  __shared__ double rloc[32];
  int t = threadIdx.x, lane = t & 63, wid = t >> 6;
  double rj = rstd[s * NA + t];
  double sq[NK];
#pragma unroll
  for (int k = 0; k < NK; k++) {
    double c = C[((size_t)s * NK + k) * NA + t];
    Cs[k][t] = c * rj;
    sq[k] = c * c;
  }
  double cn[NK];
#pragma unroll
  for (int k = 0; k < NK; k++) cn[k] = blk_sum_1024(sq[k], red16);
  const float* covS = cov + (size_t)s * NA * NA;
#pragma unroll
  for (int r2 = 0; r2 < 2; r2++) {
    int il = wid * 2 + r2;          // 0..31
    int i = rblk * 32 + il;
    const float* row = covS + (size_t)i * NA;
    double xi = xn[s * NA + i];
    double ri = rstd[s * NA + i];
    double a0 = 0, a1 = 0, a2 = 0, a3 = 0, a4 = 0;
#pragma unroll
    for (int c = 0; c < 16; c++) {
      int j = lane + (c << 6);
      double cv = (double)row[j];
      a0 += cv * Cs[0][j]; a1 += cv * Cs[1][j]; a2 += cv * Cs[2][j];
      a3 += cv * Cs[3][j]; a4 += cv * Cs[4][j];
    }
    a0 = wave_reduce64(a0); a1 = wave_reduce64(a1); a2 = wave_reduce64(a2);
    a3 = wave_reduce64(a3); a4 = wave_reduce64(a4);
    if (lane == 0) {
      double dots[5] = {a0, a1, a2, a3, a4};
      double best = INFINITY;
      int bk = 0;
#pragma unroll
      for (int k = 0; k < NK; k++) {
        double d = xi + cn[k] - 2.0 * ri * dots[k];
        if (d < 0.0) d = 0.0;
        if (d < best) { best = d; bk = k; }  // first-min like jnp.argmin
      }
      ixs[s * NA + i] = bk;
      mind[s * NA + i] = best;
      bks[il] = bk;
      rloc[il] = ri;
    }
  }
  __syncthreads();
  // partial center sums: thread t owns column t; ascending il -> deterministic
  double c0 = 0, c1 = 0, c2 = 0, c3 = 0, c4 = 0;
#pragma unroll
  for (int il = 0; il < 32; il++) {
    int i = rblk * 32 + il;
    double v = (double)covS[(size_t)i * NA + t] * rloc[il];  // L2-hot coalesced re-read
    int k = bks[il];
    c0 += (k == 0) ? v : 0.0;
    c1 += (k == 1) ? v : 0.0;
    c2 += (k == 2) ? v : 0.0;
    c3 += (k == 3) ? v : 0.0;
    c4 += (k == 4) ? v : 0.0;
  }
  double* p = pU + ((size_t)blk * NK) * NA;
  p[0 * NA + t] = c0; p[1 * NA + t] = c1; p[2 * NA + t] = c2;
  p[3 * NA + t] = c3; p[4 * NA + t] = c4;
}

__global__ __launch_bounds__(256) void k_updateB(const double* __restrict__ pU, const double* __restrict__ rstd,
                                                 const int* __restrict__ ixs, const double* __restrict__ mind,
                                                 double* __restrict__ C, double* __restrict__ pot,
                                                 int* __restrict__ conv) {
  int w = blockIdx.x, s = w >> 2, seg = w & 3, t = threadIdx.x;
  if (conv[s]) return;
  __shared__ double red4[4];
  double lc[NK] = {0, 0, 0, 0, 0};
#pragma unroll
  for (int q = 0; q < 4; q++) {
    int c = ixs[s * NA + q * 256 + t];
    lc[0] += (c == 0) ? 1.0 : 0.0;
    lc[1] += (c == 1) ? 1.0 : 0.0;
    lc[2] += (c == 2) ? 1.0 : 0.0;
    lc[3] += (c == 3) ? 1.0 : 0.0;
    lc[4] += (c == 4) ? 1.0 : 0.0;
  }
  double cntk[NK];
#pragma unroll
  for (int k = 0; k < NK; k++) cntk[k] = blk_sum_256(lc[k], red4);
  int j = seg * 256 + t;
  double rjj = rstd[s * NA + j];
  double* CS = C + (size_t)s * NK * NA;
#pragma unroll
  for (int k = 0; k < NK; k++) {
    double a = 0.0;
#pragma unroll
    for (int b = 0; b < 32; b++) {  // ascending b == ascending i: deterministic
      int blk = (s << 5) | b;
      a += pU[((size_t)blk * NK + k) * NA + j];
    }
    if (cntk[k] > 0.0) CS[(size_t)k * NA + j] = a * rjj / cntk[k];
    // empty cluster: keep previous center
  }
  if (seg == 0) {
    double v = mind[s * NA + t] + mind[s * NA + 256 + t] +
               mind[s * NA + 512 + t] + mind[s * NA + 768 + t];
    double p = blk_sum_256(v, red4);
    if (t == 0) {
      double prev = pot[s];
      pot[s] = p;
      if (!(fabs(p - prev) >= TOLER)) conv[s] = 1;  // freeze (while-cond fails)
    }
  }
}

// ---------------- post-processing ----------------
__global__ __launch_bounds__(256) void k_members(const int* __restrict__ ixs, int* __restrict__ g,
                                                 int* __restrict__ cnt, int* __restrict__ off5,
                                                 int* __restrict__ boff) {
  int s = blockIdx.x, t = threadIdx.x;
  __shared__ int sc[NK][256];
  __shared__ int base[NK];
  const int* ix = ixs + s * NA;
  int my[4];
  int lc[NK] = {0, 0, 0, 0, 0};
#pragma unroll
  for (int q = 0; q < 4; q++) { my[q] = ix[t * 4 + q]; lc[my[q]]++; }
#pragma unroll
  for (int k = 0; k < NK; k++) sc[k][t] = lc[k];
  __syncthreads();
  for (int off = 1; off < 256; off <<= 1) {
    int v[NK];
#pragma unroll
    for (int k = 0; k < NK; k++) v[k] = (t >= off) ? sc[k][t - off] : 0;
    __syncthreads();
#pragma unroll
    for (int k = 0; k < NK; k++) sc[k][t] += v[k];
    __syncthreads();
  }
  if (t == 0) {
    int b = 0, bo = 0;
    for (int k = 0; k < NK; k++) {
      int tot = sc[k][255];
      base[k] = b;
      cnt[s * NK + k] = tot;
      off5[s * NK + k] = b;
      boff[s * NK + k] = bo;
      b += tot;
      bo += tot * ((tot + 63) & ~63);  // padded: lda = align64(n)
    }
  }
  __syncthreads();
  int pos[NK];
#pragma unroll
  for (int k = 0; k < NK; k++) pos[k] = base[k] + sc[k][t] - lc[k];
#pragma unroll
  for (int q = 0; q < 4; q++) {
    int k = my[q];
    int p = pos[k]++;
    g[s * NA + p] = t * 4 + q;  // stable ascending asset order within cluster
  }
}

// Compact gather, PADDED: lda = align64(n), zero-filled pad (exact dot contributions).
__global__ __launch_bounds__(1024) void k_gatherB(const float* __restrict__ cov, const int* __restrict__ g,
                                                  const int* __restrict__ cnt, const int* __restrict__ off5,
                                                  const int* __restrict__ boff, float* __restrict__ B) {
  int w = blockIdx.x;  // 40
  int s = w / NK, k = w % NK;
  int n = cnt[s * NK + k];
  if (n == 0) return;
  int lda = (n + 63) & ~63;
  int off = off5[s * NK + k];
  __shared__ int gs[NA];
  int t = threadIdx.x, lane = t & 63, wid = t >> 6;
  if (t < n) gs[t] = g[s * NA + off + t];
  __syncthreads();
  const float* covS = cov + (size_t)s * NA * NA;
  float* Bk = B + (size_t)s * SSTRIDE + (size_t)boff[s * NK + k];
  for (int i = wid; i < n; i += 16) {
    const float* row = covS + (size_t)gs[i] * NA;
    float* out = Bk + (size_t)i * lda;
    for (int j = lane; j < lda; j += 64) out[j] = (j < n) ? row[gs[j]] : 0.0f;
  }
}

// Chronopoulos-Gear CG on padded compact block. Conflict-free scalar access
// pattern (j = lane + 64c: R7-measured 0 LDS conflicts). Sigma_cc x = 1.
__global__ __launch_bounds__(1024) void k_cg_comp(const float* __restrict__ B, const int* __restrict__ g,
                                                  const int* __restrict__ cnt, const int* __restrict__ off5,
                                                  const int* __restrict__ boff, double* __restrict__ walloc) {
  int w = blockIdx.x;  // 40
  int s = w / NK, k = w % NK;
  int n = cnt[s * NK + k];
  if (n == 0) return;
  int lda = (n + 63) & ~63;
  int nch = lda >> 6;
  int off = off5[s * NK + k];
  const float* A = B + (size_t)s * SSTRIDE + (size_t)boff[s * NK + k];
  __shared__ double xv[NA], rv[NA], pv[NA], sv[NA], wv[NA];
  __shared__ int gs[NA];
  __shared__ double redA[16], redB[16];
  int t = threadIdx.x, lane = t & 63, wid = t >> 6;
  if (t < n) gs[t] = g[s * NA + off + t];
  rv[t] = (t < n) ? 1.0 : 0.0;  // pad region zeroed: matvec reads rv up to lda
  if (t < n) xv[t] = 0.0;
  __syncthreads();
  // w = A r
  for (int i = wid; i < n; i += 16) {
    const float* row = A + (size_t)i * lda;
    double acc = 0.0;
    for (int c = 0; c < nch; c++) {
      int j = lane + (c << 6);
      acc += (double)row[j] * rv[j];
    }
    acc = wave_reduce64(acc);
    if (lane == 0) wv[i] = acc;
  }
  __syncthreads();
  double gam = (double)n;  // (r,r) with r=1
  double d1, d2;
  blk_sum2_1024((t < n) ? wv[t] : 0.0, 0.0, redA, redB, d1, d2);  // (w,r) with r=1
  double alpha = gam / d1;
  if (t < n) { pv[t] = rv[t]; sv[t] = wv[t]; }
  const double tol = 1e-10 * (double)n;  // rel resid 1e-5: err ~ kappa*1e-5*|w| << floor
  for (int iter = 0; iter < 50; iter++) {
    if (t < n) {
      xv[t] += alpha * pv[t];
      rv[t] -= alpha * sv[t];
    }
    __syncthreads();
    // w = A r
    for (int i = wid; i < n; i += 16) {
      const float* row = A + (size_t)i * lda;
      double acc = 0.0;
      for (int c = 0; c < nch; c++) {
        int j = lane + (c << 6);
        acc += (double)row[j] * rv[j];
      }
      acc = wave_reduce64(acc);
      if (lane == 0) wv[i] = acc;
    }
    __syncthreads();
    double g1 = 0.0, g2 = 0.0;
    if (t < n) {
      double rt = rv[t];
      g1 = rt * rt;
      g2 = rt * wv[t];
    }
    double gamn, delt;
    blk_sum2_1024(g1, g2, redA, redB, gamn, delt);
    if (gamn < tol) break;  // uniform across block
    double beta = gamn / gam;
    alpha = gamn / (delt - beta * gamn / alpha);
    gam = gamn;
    if (t < n) {
      pv[t] = rv[t] + beta * pv[t];
      sv[t] = wv[t] + beta * sv[t];
    }
    // no extra sync needed: next x/r update is thread-local; matvec sync covers rv
  }
  double dp = (t < n) ? xv[t] : 0.0;
  double d3, d4;
  blk_sum2_1024(dp, 0.0, redA, redB, d3, d4);
  if (t < n) walloc[s * NA + gs[t]] = xv[t] / d3;
}

// Fallback (ws too small for compact B): R5's full-row CG — verified PASS.
__global__ __launch_bounds__(1024) void k_cg_full(const float* __restrict__ cov,
                                                  const int* __restrict__ g, const int* __restrict__ cnt,
                                                  const int* __restrict__ off5, double* __restrict__ walloc) {
  int w = blockIdx.x;
  int s = w / NK, k = w % NK;
  int n = cnt[s * NK + k];
  if (n == 0) return;
  int off = off5[s * NK + k];
  const float* covS = cov + (size_t)s * NA * NA;
  __shared__ double pfull[NA];
  __shared__ double xv[NA], rv[NA], pv[NA], ap[NA];
  __shared__ int gs[NA];
  __shared__ double red16[16];
  int t = threadIdx.x, lane = t & 63, wid = t >> 6;
  if (t < n) {
    gs[t] = g[s * NA + off + t];
    xv[t] = 0.0; rv[t] = 1.0; pv[t] = 1.0;
  }
  double rr = (double)n;
  __syncthreads();
  for (int iter = 0; iter < 100; iter++) {
    pfull[t] = 0.0;
    __syncthreads();
    if (t < n) pfull[gs[t]] = pv[t];
    __syncthreads();
    for (int i = wid; i < n; i += 16) {
      const float* row = covS + (size_t)gs[i] * NA;
      double acc = 0.0;
#pragma unroll
      for (int c = 0; c < 16; c++) {
        int j = lane + (c << 6);
        acc += (double)row[j] * pfull[j];
      }
      acc = wave_reduce64(acc);
      if (lane == 0) ap[i] = acc;
    }
    __syncthreads();
    double pp = (t < n) ? pv[t] * ap[t] : 0.0;
    double pap = blk_sum_1024(pp, red16);
    double alpha = rr / pap;
    double rp = 0.0;
    if (t < n) {
      xv[t] += alpha * pv[t];
      double rn = rv[t] - alpha * ap[t];
      rv[t] = rn;
      rp = rn * rn;
    }
    double rrn = blk_sum_1024(rp, red16);
    if (rrn < 1e-20 * (double)n) break;
    double beta = rrn / rr;
    rr = rrn;
    if (t < n) pv[t] = rv[t] + beta * pv[t];
    __syncthreads();
  }
  double dp = (t < n) ? xv[t] : 0.0;
  double denom = blk_sum_1024(dp, red16);
  if (t < n) walloc[s * NA + gs[t]] = xv[t] / denom;
}

__global__ __launch_bounds__(256) void k_intery(const float* __restrict__ cov, const double* __restrict__ walloc,
                                                const int* __restrict__ g, const int* __restrict__ cnt,
                                                const int* __restrict__ off5, double* __restrict__ y2) {
  int w = blockIdx.x;  // 160
  int s = w / 20, rem = w % 20, k = rem / 4, seg = rem % 4;
  int n = cnt[s * NK + k], off = off5[s * NK + k];
  int t = threadIdx.x;
  __shared__ int gsl[NA];
  __shared__ double wl[NA];
  for (int i = t; i < n; i += 256) {
    int a = g[s * NA + off + i];
    gsl[i] = a;
    wl[i] = walloc[s * NA + a];
  }
  __syncthreads();
  int j = seg * 256 + t;
  const float* covS = cov + (size_t)s * NA * NA;
  double acc = 0.0;
  for (int i = 0; i < n; i++) acc += wl[i] * (double)covS[(size_t)gsl[i] * NA + j];
  y2[((size_t)s * NK + k) * NA + j] = acc;
}

__global__ __launch_bounds__(256) void k_icov(const double* __restrict__ y2, const double* __restrict__ walloc,
                                              const int* __restrict__ ixs, double* __restrict__ w_inter) {
  int s = blockIdx.x, t = threadIdx.x;
  __shared__ double red4[4];
  __shared__ double ic[NK * NK];
  for (int k = 0; k < NK; k++) {
    double p0 = 0, p1 = 0, p2 = 0, p3 = 0, p4 = 0;
    for (int j = t; j < NA; j += 256) {
      double v = y2[((size_t)s * NK + k) * NA + j] * walloc[s * NA + j];
      int c = ixs[s * NA + j];
      p0 += (c == 0) ? v : 0.0;
      p1 += (c == 1) ? v : 0.0;
      p2 += (c == 2) ? v : 0.0;
      p3 += (c == 3) ? v : 0.0;
      p4 += (c == 4) ? v : 0.0;
    }
    double q0 = blk_sum_256(p0, red4);
    double q1 = blk_sum_256(p1, red4);
    double q2 = blk_sum_256(p2, red4);
    double q3 = blk_sum_256(p3, red4);
    double q4 = blk_sum_256(p4, red4);
    if (t == 0) {
      ic[k * NK + 0] = q0; ic[k * NK + 1] = q1; ic[k * NK + 2] = q2;
      ic[k * NK + 3] = q3; ic[k * NK + 4] = q4;
    }
  }
  __syncthreads();
  if (t == 0) {
    double M[NK * NK], b[NK], z[NK];
    for (int i = 0; i < NK * NK; i++) M[i] = ic[i];
    for (int i = 0; i < NK; i++) b[i] = 1.0;
    for (int c = 0; c < NK; c++) {
      int pr = c;
      double mb = fabs(M[c * NK + c]);
      for (int r = c + 1; r < NK; r++) {
        double a = fabs(M[r * NK + c]);
        if (a > mb) { mb = a; pr = r; }
      }
      if (pr != c) {
        for (int cc = 0; cc < NK; cc++) {
          double tmp = M[c * NK + cc]; M[c * NK + cc] = M[pr * NK + cc]; M[pr * NK + cc] = tmp;
        }
        double tb = b[c]; b[c] = b[pr]; b[pr] = tb;
      }
      double piv = M[c * NK + c];
      for (int r = c + 1; r < NK; r++) {
        double f = M[r * NK + c] / piv;
        for (int cc = c; cc < NK; cc++) M[r * NK + cc] -= f * M[c * NK + cc];
        b[r] -= f * b[c];
      }
    }
    for (int r = NK - 1; r >= 0; r--) {
      double acc = b[r];
      for (int cc = r + 1; cc < NK; cc++) acc -= M[r * NK + cc] * z[cc];
      z[r] = acc / M[r * NK + r];
    }
    double ssum = z[0] + z[1] + z[2] + z[3] + z[4];
    for (int k = 0; k < NK; k++) w_inter[s * NK + k] = z[k] / ssum;
  }
}

__global__ __launch_bounds__(256) void k_final(const double* __restrict__ walloc, const double* __restrict__ w_inter,
                                               const int* __restrict__ ixs, float* __restrict__ out) {
  int gid = blockIdx.x * 256 + threadIdx.x;
  if (gid >= NS * NA) return;
  int s = gid >> 10;
  out[gid] = (float)(walloc[gid] * w_inter[s * NK + ixs[gid]]);
}

// ---------------- launch ----------------
extern "C" void kernel_launch(void* const* d_in, const int* in_sizes, int n_in,
                              void* d_out, int out_size, void* d_ws, size_t ws_size,
                              hipStream_t stream) {
  const float* cov = (const float*)d_in[0];
  float* out = (float*)d_out;
  char* ws = (char*)d_ws;
  size_t o = 0;
  auto alloc = [&](size_t bytes) {
    size_t cur = o;
    o += (bytes + 255) & ~(size_t)255;
    return cur;
  };
  double* C = (double*)(ws + alloc((size_t)NS * NK * NA * 8));
  double* y2 = (double*)(ws + alloc((size_t)NS * NK * NA * 8));
  double* pU = (double*)(ws + alloc((size_t)256 * NK * NA * 8));  // 10.5 MB partials
  double* rstd = (double*)(ws + alloc((size_t)NS * NA * 8));
  double* xn = (double*)(ws + alloc((size_t)NS * NA * 8));
  double* mind = (double*)(ws + alloc((size_t)NS * NA * 8));
  double* walloc = (double*)(ws + alloc((size_t)NS * NA * 8));
  int* ixs = (int*)(ws + alloc((size_t)NS * NA * 4));
  int* g = (int*)(ws + alloc((size_t)NS * NA * 4));
  int* cnt = (int*)(ws + alloc((size_t)NS * NK * 4));
  int* off5 = (int*)(ws + alloc((size_t)NS * NK * 4));
  int* boff = (int*)(ws + alloc((size_t)NS * NK * 4));
  int* conv = (int*)(ws + alloc((size_t)NS * 4));
  double* pot = (double*)(ws + alloc((size_t)NS * 8));
  double* w_inter = (double*)(ws + alloc((size_t)NS * NK * 8));
  size_t bcomp_off = alloc(NS * SSTRIDE * 4);  // 35.7 MB padded blocks, guarded
  float* Bcomp = (float*)(ws + bcomp_off);
  bool use_compact = (ws_size >= o);  // launch-time constant: same graph every call
  (void)in_sizes; (void)n_in; (void)out_size;

  InitIdx ii;
  compute_init_indices(ii);  // data-independent, identical every call

  k_pre<<<553, 256, 0, stream>>>(cov, rstd, xn, C, ii, pot, conv);
  for (int it = 0; it < MAXIT; it++) {
    k_assignA<<<256, 1024, 0, stream>>>(cov, rstd, xn, C, conv, ixs, mind, pU);
    k_updateB<<<32, 256, 0, stream>>>(pU, rstd, ixs, mind, C, pot, conv);
  }
  k_members<<<8, 256, 0, stream>>>(ixs, g, cnt, off5, boff);
  if (use_compact) {
    k_gatherB<<<40, 1024, 0, stream>>>(cov, g, cnt, off5, boff, Bcomp);
    k_cg_comp<<<40, 1024, 0, stream>>>(Bcomp, g, cnt, off5, boff, walloc);
  } else {
    k_cg_full<<<40, 1024, 0, stream>>>(cov, g, cnt, off5, walloc);
  }
  k_intery<<<160, 256, 0, stream>>>(cov, walloc, g, cnt, off5, y2);
  k_icov<<<8, 256, 0, stream>>>(y2, walloc, ixs, w_inter);
  k_final<<<32, 256, 0, stream>>>(walloc, w_inter, ixs, out);
}